// Round 7
// baseline (968.420 us; speedup 1.0000x reference)
//
#include <hip/hip_runtime.h>
#include <stdint.h>
#include <math.h>

typedef unsigned short u16;
typedef unsigned int   u32;
typedef unsigned long long u64;
typedef __attribute__((ext_vector_type(8))) short bf16x8;
typedef __attribute__((ext_vector_type(4))) float f32x4;

#define NB   4
#define NQ   4096
#define NPT  2048
#define DIM  256
#define KNN_ 16

// ---------------- module-global scratch (no d_ws dependence) ----------------
__device__ int   g_isbf16;
__device__ int   g_knn[NB * NQ * KNN_];        // 1 MB
__device__ float g_qattn[NB * DIM];
__device__ float g_vglob[NB * DIM];
__device__ float g_attng[NB * DIM];
// fragment-ordered packed weights: [mat][ct][kt][lane][8] ; mats: Wd2,Wk,Wv,Wg1,Wg2
__device__ u16   g_wpack[5 * DIM * DIM];       // 640 KB

__device__ __forceinline__ float bf2f(u16 u) {
    union { u32 i; float f; } v; v.i = ((u32)u) << 16; return v.f;
}
__device__ __forceinline__ u16 f2bf(float f) {
    union { float f; u32 i; } v; v.f = f;
    u32 u = v.i;
    return (u16)((u + 0x7FFFu + ((u >> 16) & 1u)) >> 16);
}
// dtype-agnostic scalar load
template<int BF16>
__device__ __forceinline__ float ldf(const void* p, size_t i) {
    if (BF16) return bf2f(((const u16*)p)[i]);
    return ((const float*)p)[i];
}
// dtype-agnostic 8-element fragment load -> bf16x8 (16B-aligned in both modes)
template<int BF16>
__device__ __forceinline__ bf16x8 ldfrag(const void* p, size_t i) {
    if (BF16) return *(const bf16x8*)((const u16*)p + i);
    const float* f = (const float*)p + i;
    float4 a = *(const float4*)f;
    float4 b = *(const float4*)(f + 4);
    bf16x8 r;
    r[0] = (short)f2bf(a.x); r[1] = (short)f2bf(a.y);
    r[2] = (short)f2bf(a.z); r[3] = (short)f2bf(a.w);
    r[4] = (short)f2bf(b.x); r[5] = (short)f2bf(b.y);
    r[6] = (short)f2bf(b.z); r[7] = (short)f2bf(b.w);
    return r;
}
// XOR-swizzled element address inside a [rows][256] bf16 LDS tile
__device__ __forceinline__ int swz(int r, int c) {
    return r * DIM + ((((c >> 3) ^ (r & 7))) << 3) + (c & 7);
}

// ---------------------------------------------------------------------------
// Probe: classify input dtype from lat_rep bit patterns.
// ---------------------------------------------------------------------------
__global__ void probe_kernel(const u32* __restrict__ lat)
{
    if (threadIdx.x == 0 && blockIdx.x == 0) {
        int cnt = 0;
        for (int i = 0; i < 64; ++i) {
            u32 e = (lat[i] >> 7) & 0xFF;
            cnt += (e >= 110 && e <= 133) ? 1 : 0;
        }
        g_isbf16 = (cnt >= 32) ? 1 : 0;
    }
}

// ---------------------------------------------------------------------------
// Repack the 5 hot weight matrices into MFMA-fragment order:
// dst[(((ct*8+kt)*4+q4)*16+l15)*8 + j] = W[ct*16+l15][kt*32+q4*8+j]
// ---------------------------------------------------------------------------
template<int BF16>
__global__ __launch_bounds__(256) void repack_kernel(
    const void* __restrict__ Wd2, const void* __restrict__ Wk,
    const void* __restrict__ Wv,  const void* __restrict__ Wg1,
    const void* __restrict__ Wg2)
{
    if (g_isbf16 != BF16) return;
    const void* srcs[5] = { Wd2, Wk, Wv, Wg1, Wg2 };
    const int m   = blockIdx.y;
    const int tid = blockIdx.x * 256 + threadIdx.x;   // 0..8191
    const int ct  = tid >> 9;
    const int kt  = (tid >> 6) & 7;
    const int q4  = (tid >> 4) & 3;
    const int l15 = tid & 15;
    const int row = ct * 16 + l15;
    const int col = (kt << 5) + (q4 << 3);
    bf16x8 v = ldfrag<BF16>(srcs[m], (size_t)row * DIM + col);
    *(bf16x8*)(g_wpack + m * DIM * DIM + (tid << 3)) = v;
}

// ---------------------------------------------------------------------------
// Kernel A: exact 16-NN per query. f64 distances, index in low mantissa bits.
// ---------------------------------------------------------------------------
template<int BF16>
__global__ __launch_bounds__(256) void knn_kernel(const void* __restrict__ xyz_q,
                                                  const void* __restrict__ xyz)
{
    if (g_isbf16 != BF16) return;
    __shared__ float4 pts[NPT];                  // 32 KB
    const int b  = blockIdx.x >> 10;
    const int q0 = (blockIdx.x & 1023) << 2;
    const int t  = threadIdx.x;
    for (int i = t; i < NPT; i += 256) {
        const size_t base = ((size_t)b * NPT + i) * 3;
        pts[i] = make_float4(ldf<BF16>(xyz, base + 0),
                             ldf<BF16>(xyz, base + 1),
                             ldf<BF16>(xyz, base + 2), 0.f);
    }
    __syncthreads();

    const int w = t >> 6, lane = t & 63;
    const int q = q0 + w;
    const size_t qb = ((size_t)b * NQ + q) * 3;
    const double qx = (double)ldf<BF16>(xyz_q, qb + 0);
    const double qy = (double)ldf<BF16>(xyz_q, qb + 1);
    const double qz = (double)ldf<BF16>(xyz_q, qb + 2);

    u64 key[32];
    #pragma unroll
    for (int i = 0; i < 32; ++i) {
        const int n = (i << 6) + lane;
        float4 p = pts[n];
        double dx = qx - (double)p.x;
        double dy = qy - (double)p.y;
        double dz = qz - (double)p.z;
        double d2 = fma(dx, dx, fma(dy, dy, dz * dz));   // >= 0
        key[i] = (((u64)__double_as_longlong(d2)) & 0xFFFFFFFFFFFFF800ULL) | (u64)n;
    }
    u64 gmin[4];
    #pragma unroll
    for (int j = 0; j < 4; ++j) {
        u64 mn = key[8 * j];
        #pragma unroll
        for (int i = 1; i < 8; ++i) { u64 k2 = key[8 * j + i]; mn = k2 < mn ? k2 : mn; }
        gmin[j] = mn;
    }
    int* outp = g_knn + ((size_t)b * NQ + q) * KNN_;
    #pragma unroll 1
    for (int r = 0; r < KNN_; ++r) {
        u64 m01 = gmin[0] < gmin[1] ? gmin[0] : gmin[1];
        u64 m23 = gmin[2] < gmin[3] ? gmin[2] : gmin[3];
        u64 m   = m01 < m23 ? m01 : m23;
        #pragma unroll
        for (int off = 32; off >= 1; off >>= 1) {
            u64 o = __shfl_xor(m, off);
            m = o < m ? o : m;
        }
        if (lane == 0) outp[r] = (int)(m & 0x7FF);
        #pragma unroll
        for (int j = 0; j < 4; ++j) {
            if (gmin[j] == m) {
                u64 mn = ~0ULL;
                #pragma unroll
                for (int i = 0; i < 8; ++i) {
                    u64 k2 = key[8 * j + i];
                    k2 = (k2 == m) ? ~0ULL : k2;
                    key[8 * j + i] = k2;
                    mn = k2 < mn ? k2 : mn;
                }
                gmin[j] = mn;
            }
        }
    }
}

// ---------------------------------------------------------------------------
// Kernel B: per-batch q_attn, v_global, attn_g = MLP2(q_attn - k_global).
// ---------------------------------------------------------------------------
template<int BF16>
__global__ __launch_bounds__(256) void gtok_kernel(const void* __restrict__ lat,
    const void* __restrict__ Wq,  const void* __restrict__ Wkg, const void* __restrict__ Wvg,
    const void* __restrict__ Wg1, const void* __restrict__ bg1,
    const void* __restrict__ Wg2, const void* __restrict__ bg2)
{
    if (g_isbf16 != BF16) return;
    const int b = blockIdx.x, t = threadIdx.x;
    __shared__ float latS[DIM], xS[DIM], hS[DIM];
    latS[t] = ldf<BF16>(lat, (size_t)b * DIM + t);
    __syncthreads();
    float sq = 0.f, sk = 0.f, sv = 0.f;
    for (int i = 0; i < DIM; ++i) {
        float x = latS[i];
        sq += x * ldf<BF16>(Wq,  (size_t)t * DIM + i);
        sk += x * ldf<BF16>(Wkg, (size_t)t * DIM + i);
        sv += x * ldf<BF16>(Wvg, (size_t)t * DIM + i);
    }
    g_qattn[b * DIM + t] = sq;
    g_vglob[b * DIM + t] = sv;
    xS[t] = sq - sk;
    __syncthreads();
    float h = 0.f;
    for (int i = 0; i < DIM; ++i) h += xS[i] * ldf<BF16>(Wg1, (size_t)t * DIM + i);
    h += ldf<BF16>(bg1, t);
    hS[t] = fmaxf(h, 0.f);
    __syncthreads();
    float a = 0.f;
    for (int i = 0; i < DIM; ++i) a += hS[i] * ldf<BF16>(Wg2, (size_t)t * DIM + i);
    a += ldf<BF16>(bg2, t);
    g_attng[b * DIM + t] = a;
}

// ---------------------------------------------------------------------------
// Kernel C: fused attention. Block = 8 queries = 128 rows, 4 waves,
// 2 queries (2 row-tiles) per wave -> each B-fragment load feeds 2 MFMAs.
// vp = bf16(V+pos) kept in 64 packed VGPRs (no bufVP). Raw s_barrier per
// ct keeps waves lockstep so identical weight-fragment reads hit L1.
// ---------------------------------------------------------------------------
template<int BF16>
__global__ __launch_bounds__(256, 1) void attn_kernel(
    const void* __restrict__ xyz_q, const void* __restrict__ xyz,
    const void* __restrict__ points,
    const void* __restrict__ Wd1, const void* __restrict__ bd1,
    const void* __restrict__ bd2, const void* __restrict__ bg1,
    const void* __restrict__ bg2,
    void* __restrict__ out)
{
    if (g_isbf16 != BF16) return;
    __shared__ u16 bufA[128 * DIM];              // 64 KB swizzled activations
    __shared__ int nbrS[128];
    __shared__ float wd1S[DIM * 4];              // (w0,w1,w2,bd1) per output col
    __shared__ float qaS[DIM], agS[DIM], vgS[DIM];
    __shared__ float bd2S[DIM], bg1S[DIM], bg2S[DIM];

    const int b  = blockIdx.x >> 9;
    const int q0 = (blockIdx.x & 511) << 3;
    const int t  = threadIdx.x;

    // ---- stage 0: small shared data (the ONLY full __syncthreads barrier)
    wd1S[t * 4 + 0] = ldf<BF16>(Wd1, (size_t)t * 3 + 0);
    wd1S[t * 4 + 1] = ldf<BF16>(Wd1, (size_t)t * 3 + 1);
    wd1S[t * 4 + 2] = ldf<BF16>(Wd1, (size_t)t * 3 + 2);
    wd1S[t * 4 + 3] = ldf<BF16>(bd1, t);
    bd2S[t] = ldf<BF16>(bd2, t);
    bg1S[t] = ldf<BF16>(bg1, t);
    bg2S[t] = ldf<BF16>(bg2, t);
    qaS[t] = g_qattn[b * DIM + t];
    agS[t] = g_attng[b * DIM + t];
    vgS[t] = g_vglob[b * DIM + t];
    if (t < 128) {
        int qq = q0 + (t >> 4);
        nbrS[t] = g_knn[((size_t)b * NQ + qq) * KNN_ + (t & 15)];
    }
    __syncthreads();

    const int w = t >> 6, lane = t & 63;
    const int rw2 = w << 5;                      // this wave's 32 rows
    const int q4 = lane >> 4, l15 = lane & 15;
    const int arow0 = rw2 + l15;
    const int arow1 = arow0 + 16;

    // packed-weight bases (fragment order): frag index = (ct*8+kt)*64 + lane
    const u16* WpD2 = g_wpack + 0 * DIM * DIM;
    const u16* WpK  = g_wpack + 1 * DIM * DIM;
    const u16* WpV  = g_wpack + 2 * DIM * DIM;
    const u16* WpG1 = g_wpack + 3 * DIM * DIM;
    const u16* WpG2 = g_wpack + 4 * DIM * DIM;

    // ---- gathered P-fragments for both tiles (issued early)
    const size_t prow0 = ((size_t)b * NPT + nbrS[arow0]) * DIM;
    const size_t prow1 = ((size_t)b * NPT + nbrS[arow1]) * DIM;
    bf16x8 afrP0[8], afrP1[8];
    #pragma unroll
    for (int kt = 0; kt < 8; ++kt) {
        afrP0[kt] = ldfrag<BF16>(points, prow0 + ((((kt << 2) + q4)) << 3));
        afrP1[kt] = ldfrag<BF16>(points, prow1 + ((((kt << 2) + q4)) << 3));
    }

    // ---- stage 1: h1 = relu(d @ Wd1^T + bd1) -> bufA, wave-private 32 rows
    {
        const int rloc = lane >> 1;              // 0..31
        const int r    = rw2 + rloc;
        const int qv   = q0 + (r >> 4);
        const int n    = nbrS[r];
        const size_t nb3 = ((size_t)b * NPT + n) * 3;
        const size_t qb3 = ((size_t)b * NQ + qv) * 3;
        const float dx = ldf<BF16>(xyz_q, qb3 + 0) - ldf<BF16>(xyz, nb3 + 0);
        const float dy = ldf<BF16>(xyz_q, qb3 + 1) - ldf<BF16>(xyz, nb3 + 1);
        const float dz = ldf<BF16>(xyz_q, qb3 + 2) - ldf<BF16>(xyz, nb3 + 2);
        const int half = lane & 1;
        #pragma unroll
        for (int ci = 0; ci < 16; ++ci) {
            const int kc = (ci << 1) + half;
            u32 hw[4];
            #pragma unroll
            for (int pp = 0; pp < 4; ++pp) {
                const int c = (kc << 3) + pp * 2;
                const float* wv0 = wd1S + (size_t)c * 4;
                const float* wv1 = wd1S + (size_t)(c + 1) * 4;
                float h0 = wv0[0] * dx + wv0[1] * dy + wv0[2] * dz + wv0[3];
                float h1 = wv1[0] * dx + wv1[1] * dy + wv1[2] * dz + wv1[3];
                hw[pp] = (u32)f2bf(fmaxf(h0, 0.f)) | ((u32)f2bf(fmaxf(h1, 0.f)) << 16);
            }
            *(uint4*)(bufA + r * DIM + ((kc ^ (r & 7)) << 3)) = make_uint4(hw[0], hw[1], hw[2], hw[3]);
        }
    }
    // no barrier: rows are wave-private; in-wave LDS RAW handled by waitcnt

    // h1 fragments from LDS (both tiles)
    bf16x8 afrA0[8], afrA1[8];
    #pragma unroll
    for (int kt = 0; kt < 8; ++kt) {
        afrA0[kt] = *(const bf16x8*)(bufA + arow0 * DIM + ((((kt << 2) + q4) ^ (arow0 & 7)) << 3));
        afrA1[kt] = *(const bf16x8*)(bufA + arow1 * DIM + ((((kt << 2) + q4) ^ (arow1 & 7)) << 3));
    }

    // ---- stage 2: pos/K/V for both tiles; attn_in -> bufA; vp -> regs
    u32 vp0[32], vp1[32];
    #pragma unroll 1
    for (int ct = 0; ct < 16; ++ct) {
        __builtin_amdgcn_s_barrier();            // lockstep for L1 reuse
        const int colg = (ct << 4) + l15;
        const int fbase = ((ct << 3) * 64 + lane) << 3;   // + kt*512 per kt
        f32x4 aP0 = {0.f,0.f,0.f,0.f}, aK0 = {0.f,0.f,0.f,0.f}, aV0 = {0.f,0.f,0.f,0.f};
        f32x4 aP1 = {0.f,0.f,0.f,0.f}, aK1 = {0.f,0.f,0.f,0.f}, aV1 = {0.f,0.f,0.f,0.f};
        #pragma unroll
        for (int kt = 0; kt < 8; ++kt) {
            const int fo = fbase + (kt << 9);
            bf16x8 bfrD = *(const bf16x8*)(WpD2 + fo);
            bf16x8 bfrK = *(const bf16x8*)(WpK  + fo);
            bf16x8 bfrV = *(const bf16x8*)(WpV  + fo);
            aP0 = __builtin_amdgcn_mfma_f32_16x16x32_bf16(afrA0[kt], bfrD, aP0, 0, 0, 0);
            aP1 = __builtin_amdgcn_mfma_f32_16x16x32_bf16(afrA1[kt], bfrD, aP1, 0, 0, 0);
            aK0 = __builtin_amdgcn_mfma_f32_16x16x32_bf16(afrP0[kt], bfrK, aK0, 0, 0, 0);
            aK1 = __builtin_amdgcn_mfma_f32_16x16x32_bf16(afrP1[kt], bfrK, aK1, 0, 0, 0);
            aV0 = __builtin_amdgcn_mfma_f32_16x16x32_bf16(afrP0[kt], bfrV, aV0, 0, 0, 0);
            aV1 = __builtin_amdgcn_mfma_f32_16x16x32_bf16(afrP1[kt], bfrV, aV1, 0, 0, 0);
        }
        const float bb = bd2S[colg];
        const float qa = qaS[colg];
        u16 pb[4];
        #pragma unroll
        for (int reg = 0; reg < 4; ++reg) {
            const float pv = aP0[reg] + bb;
            pb[reg] = f2bf(aV0[reg] + pv);
            const int rr = rw2 + (q4 << 2) + reg;
            bufA[swz(rr, colg)] = f2bf((qa - aK0[reg]) + pv);
        }
        vp0[(ct << 1) + 0] = (u32)pb[0] | ((u32)pb[1] << 16);
        vp0[(ct << 1) + 1] = (u32)pb[2] | ((u32)pb[3] << 16);
        #pragma unroll
        for (int reg = 0; reg < 4; ++reg) {
            const float pv = aP1[reg] + bb;
            pb[reg] = f2bf(aV1[reg] + pv);
            const int rr = rw2 + 16 + (q4 << 2) + reg;
            bufA[swz(rr, colg)] = f2bf((qa - aK1[reg]) + pv);
        }
        vp1[(ct << 1) + 0] = (u32)pb[0] | ((u32)pb[1] << 16);
        vp1[(ct << 1) + 1] = (u32)pb[2] | ((u32)pb[3] << 16);
    }

    // ---- stage 3: g1 = relu(attn_in@Wg1^T + bg1) -> bufA
    #pragma unroll
    for (int kt = 0; kt < 8; ++kt) {
        afrA0[kt] = *(const bf16x8*)(bufA + arow0 * DIM + ((((kt << 2) + q4) ^ (arow0 & 7)) << 3));
        afrA1[kt] = *(const bf16x8*)(bufA + arow1 * DIM + ((((kt << 2) + q4) ^ (arow1 & 7)) << 3));
    }
    #pragma unroll 1
    for (int ct = 0; ct < 16; ++ct) {
        __builtin_amdgcn_s_barrier();
        const int colg = (ct << 4) + l15;
        const int fbase = ((ct << 3) * 64 + lane) << 3;
        f32x4 a0 = {0.f,0.f,0.f,0.f}, a1 = {0.f,0.f,0.f,0.f};
        #pragma unroll
        for (int kt = 0; kt < 8; ++kt) {
            bf16x8 bfr = *(const bf16x8*)(WpG1 + fbase + (kt << 9));
            a0 = __builtin_amdgcn_mfma_f32_16x16x32_bf16(afrA0[kt], bfr, a0, 0, 0, 0);
            a1 = __builtin_amdgcn_mfma_f32_16x16x32_bf16(afrA1[kt], bfr, a1, 0, 0, 0);
        }
        const float bb = bg1S[colg];
        #pragma unroll
        for (int reg = 0; reg < 4; ++reg) {
            bufA[swz(rw2      + (q4 << 2) + reg, colg)] = f2bf(fmaxf(a0[reg] + bb, 0.f));
            bufA[swz(rw2 + 16 + (q4 << 2) + reg, colg)] = f2bf(fmaxf(a1[reg] + bb, 0.f));
        }
    }

    // ---- stage 4: logits; softmax over 16 nbrs + global; output (2 queries)
    #pragma unroll
    for (int kt = 0; kt < 8; ++kt) {
        afrA0[kt] = *(const bf16x8*)(bufA + arow0 * DIM + ((((kt << 2) + q4) ^ (arow0 & 7)) << 3));
        afrA1[kt] = *(const bf16x8*)(bufA + arow1 * DIM + ((((kt << 2) + q4) ^ (arow1 & 7)) << 3));
    }
    const int qA = q0 + (w << 1);
    const size_t outqA = ((size_t)b * NQ + qA) * DIM;
    const size_t outqB = outqA + DIM;
    const float LOG2E = 1.4426950408889634f;
    #pragma unroll 1
    for (int ct = 0; ct < 16; ++ct) {
        __builtin_amdgcn_s_barrier();
        const int colg = (ct << 4) + l15;
        const int fbase = ((ct << 3) * 64 + lane) << 3;
        f32x4 aL0 = {0.f,0.f,0.f,0.f}, aL1 = {0.f,0.f,0.f,0.f};
        #pragma unroll
        for (int kt = 0; kt < 8; ++kt) {
            bf16x8 bfrG = *(const bf16x8*)(WpG2 + fbase + (kt << 9));
            aL0 = __builtin_amdgcn_mfma_f32_16x16x32_bf16(afrA0[kt], bfrG, aL0, 0, 0, 0);
            aL1 = __builtin_amdgcn_mfma_f32_16x16x32_bf16(afrA1[kt], bfrG, aL1, 0, 0, 0);
        }
        const float bb = bg2S[colg];
        const float gl = fminf(30.f, fmaxf(-30.f, agS[colg]));
        const float vg = vgS[colg];
        #pragma unroll
        for (int tt = 0; tt < 2; ++tt) {
            const f32x4& aL = tt ? aL1 : aL0;
            const u32* vp   = tt ? vp1 : vp0;
            const float l0 = fminf(30.f, fmaxf(-30.f, aL[0] + bb));
            const float l1 = fminf(30.f, fmaxf(-30.f, aL[1] + bb));
            const float l2 = fminf(30.f, fmaxf(-30.f, aL[2] + bb));
            const float l3 = fminf(30.f, fmaxf(-30.f, aL[3] + bb));
            float mx = fmaxf(fmaxf(l0, l1), fmaxf(l2, l3));
            mx = fmaxf(mx, __shfl_xor(mx, 16));
            mx = fmaxf(mx, __shfl_xor(mx, 32));
            mx = fmaxf(mx, gl);
            const float e0 = exp2f((l0 - mx) * LOG2E), e1 = exp2f((l1 - mx) * LOG2E);
            const float e2 = exp2f((l2 - mx) * LOG2E), e3 = exp2f((l3 - mx) * LOG2E);
            float s = (e0 + e1) + (e2 + e3);
            s += __shfl_xor(s, 16);
            s += __shfl_xor(s, 32);
            const float eg  = exp2f((gl - mx) * LOG2E);
            const float inv = 1.0f / (s + eg);
            const u32 p01 = vp[(ct << 1) + 0];
            const u32 p23 = vp[(ct << 1) + 1];
            float o = e0 * bf2f((u16)(p01 & 0xFFFF))
                    + e1 * bf2f((u16)(p01 >> 16))
                    + e2 * bf2f((u16)(p23 & 0xFFFF))
                    + e3 * bf2f((u16)(p23 >> 16));
            o += __shfl_xor(o, 16);
            o += __shfl_xor(o, 32);
            o = (o + eg * vg) * inv;
            if (lane < 16) {
                const size_t oq = tt ? outqB : outqA;
                if (BF16) ((u16*)out)[oq + colg] = f2bf(o);
                else      ((float*)out)[oq + colg] = o;
            }
        }
    }
}

// ---------------------------------------------------------------------------
extern "C" void kernel_launch(void* const* d_in, const int* in_sizes, int n_in,
                              void* d_out, int out_size, void* d_ws, size_t ws_size,
                              hipStream_t stream)
{
    const void* xyz_q  = d_in[0];
    const void* lat    = d_in[1];
    const void* xyz    = d_in[2];
    const void* points = d_in[3];
    const void* Wd1 = d_in[4];
    const void* bd1 = d_in[5];
    const void* Wd2 = d_in[6];
    const void* bd2 = d_in[7];
    const void* Wg1 = d_in[8];
    const void* bg1 = d_in[9];
    const void* Wg2 = d_in[10];
    const void* bg2 = d_in[11];
    const void* Wkg = d_in[12];
    const void* Wvg = d_in[13];
    const void* Wq  = d_in[14];
    const void* Wk  = d_in[15];
    const void* Wv  = d_in[16];

    probe_kernel<<<1, 64, 0, stream>>>((const u32*)lat);

    repack_kernel<1><<<dim3(32, 5), 256, 0, stream>>>(Wd2, Wk, Wv, Wg1, Wg2);
    repack_kernel<0><<<dim3(32, 5), 256, 0, stream>>>(Wd2, Wk, Wv, Wg1, Wg2);
    knn_kernel<1><<<4096, 256, 0, stream>>>(xyz_q, xyz);
    knn_kernel<0><<<4096, 256, 0, stream>>>(xyz_q, xyz);
    gtok_kernel<1><<<4, 256, 0, stream>>>(lat, Wq, Wkg, Wvg, Wg1, bg1, Wg2, bg2);
    gtok_kernel<0><<<4, 256, 0, stream>>>(lat, Wq, Wkg, Wvg, Wg1, bg1, Wg2, bg2);
    attn_kernel<1><<<2048, 256, 0, stream>>>(xyz_q, xyz, points,
                                             Wd1, bd1, bd2, bg1, bg2, d_out);
    attn_kernel<0><<<2048, 256, 0, stream>>>(xyz_q, xyz, points,
                                             Wd1, bd1, bd2, bg1, bg2, d_out);
}

// Round 8
// 705.683 us; speedup vs baseline: 1.3723x; 1.3723x over previous
//
#include <hip/hip_runtime.h>
#include <stdint.h>
#include <math.h>

typedef unsigned short u16;
typedef unsigned int   u32;
typedef unsigned long long u64;
typedef __attribute__((ext_vector_type(8))) short bf16x8;
typedef __attribute__((ext_vector_type(4))) float f32x4;

#define NB   4
#define NQ   4096
#define NPT  2048
#define DIM  256
#define KNN_ 16

// ---------------- module-global scratch (no d_ws dependence) ----------------
__device__ int   g_isbf16;
__device__ int   g_knn[NB * NQ * KNN_];        // 1 MB
__device__ float g_qattn[NB * DIM];
__device__ float g_vglob[NB * DIM];
__device__ float g_attng[NB * DIM];
// fragment-ordered packed weights: [mat][ct][kt][lane][8] ; mats: Wd2,Wk,Wv,Wg1,Wg2
__device__ u16   g_wpack[5 * DIM * DIM];       // 640 KB

__device__ __forceinline__ float bf2f(u16 u) {
    union { u32 i; float f; } v; v.i = ((u32)u) << 16; return v.f;
}
__device__ __forceinline__ u16 f2bf(float f) {
    union { float f; u32 i; } v; v.f = f;
    u32 u = v.i;
    return (u16)((u + 0x7FFFu + ((u >> 16) & 1u)) >> 16);
}
// dtype-agnostic scalar load
template<int BF16>
__device__ __forceinline__ float ldf(const void* p, size_t i) {
    if (BF16) return bf2f(((const u16*)p)[i]);
    return ((const float*)p)[i];
}
// dtype-agnostic 8-element fragment load -> bf16x8 (16B-aligned in both modes)
template<int BF16>
__device__ __forceinline__ bf16x8 ldfrag(const void* p, size_t i) {
    if (BF16) return *(const bf16x8*)((const u16*)p + i);
    const float* f = (const float*)p + i;
    float4 a = *(const float4*)f;
    float4 b = *(const float4*)(f + 4);
    bf16x8 r;
    r[0] = (short)f2bf(a.x); r[1] = (short)f2bf(a.y);
    r[2] = (short)f2bf(a.z); r[3] = (short)f2bf(a.w);
    r[4] = (short)f2bf(b.x); r[5] = (short)f2bf(b.y);
    r[6] = (short)f2bf(b.z); r[7] = (short)f2bf(b.w);
    return r;
}
// XOR-swizzled element address inside a [rows][256] bf16 LDS tile
__device__ __forceinline__ int swz(int r, int c) {
    return r * DIM + ((((c >> 3) ^ (r & 7))) << 3) + (c & 7);
}

// ---------------------------------------------------------------------------
// Probe: classify input dtype from lat_rep bit patterns.
// ---------------------------------------------------------------------------
__global__ void probe_kernel(const u32* __restrict__ lat)
{
    if (threadIdx.x == 0 && blockIdx.x == 0) {
        int cnt = 0;
        for (int i = 0; i < 64; ++i) {
            u32 e = (lat[i] >> 7) & 0xFF;
            cnt += (e >= 110 && e <= 133) ? 1 : 0;
        }
        g_isbf16 = (cnt >= 32) ? 1 : 0;
    }
}

// ---------------------------------------------------------------------------
// Repack the 5 hot weight matrices into MFMA-fragment order:
// dst[(((ct*8+kt)*4+q4)*16+l15)*8 + j] = W[ct*16+l15][kt*32+q4*8+j]
// ---------------------------------------------------------------------------
template<int BF16>
__global__ __launch_bounds__(256) void repack_kernel(
    const void* __restrict__ Wd2, const void* __restrict__ Wk,
    const void* __restrict__ Wv,  const void* __restrict__ Wg1,
    const void* __restrict__ Wg2)
{
    if (g_isbf16 != BF16) return;
    const void* srcs[5] = { Wd2, Wk, Wv, Wg1, Wg2 };
    const int m   = blockIdx.y;
    const int tid = blockIdx.x * 256 + threadIdx.x;   // 0..8191
    const int ct  = tid >> 9;
    const int kt  = (tid >> 6) & 7;
    const int q4  = (tid >> 4) & 3;
    const int l15 = tid & 15;
    const int row = ct * 16 + l15;
    const int col = (kt << 5) + (q4 << 3);
    bf16x8 v = ldfrag<BF16>(srcs[m], (size_t)row * DIM + col);
    *(bf16x8*)(g_wpack + m * DIM * DIM + (tid << 3)) = v;
}

// ---------------------------------------------------------------------------
// Kernel A: exact 16-NN per query. f64 distances, index in low mantissa bits.
// ---------------------------------------------------------------------------
template<int BF16>
__global__ __launch_bounds__(256) void knn_kernel(const void* __restrict__ xyz_q,
                                                  const void* __restrict__ xyz)
{
    if (g_isbf16 != BF16) return;
    __shared__ float4 pts[NPT];                  // 32 KB
    const int b  = blockIdx.x >> 10;
    const int q0 = (blockIdx.x & 1023) << 2;
    const int t  = threadIdx.x;
    for (int i = t; i < NPT; i += 256) {
        const size_t base = ((size_t)b * NPT + i) * 3;
        pts[i] = make_float4(ldf<BF16>(xyz, base + 0),
                             ldf<BF16>(xyz, base + 1),
                             ldf<BF16>(xyz, base + 2), 0.f);
    }
    __syncthreads();

    const int w = t >> 6, lane = t & 63;
    const int q = q0 + w;
    const size_t qb = ((size_t)b * NQ + q) * 3;
    const double qx = (double)ldf<BF16>(xyz_q, qb + 0);
    const double qy = (double)ldf<BF16>(xyz_q, qb + 1);
    const double qz = (double)ldf<BF16>(xyz_q, qb + 2);

    u64 key[32];
    #pragma unroll
    for (int i = 0; i < 32; ++i) {
        const int n = (i << 6) + lane;
        float4 p = pts[n];
        double dx = qx - (double)p.x;
        double dy = qy - (double)p.y;
        double dz = qz - (double)p.z;
        double d2 = fma(dx, dx, fma(dy, dy, dz * dz));   // >= 0
        key[i] = (((u64)__double_as_longlong(d2)) & 0xFFFFFFFFFFFFF800ULL) | (u64)n;
    }
    u64 gmin[4];
    #pragma unroll
    for (int j = 0; j < 4; ++j) {
        u64 mn = key[8 * j];
        #pragma unroll
        for (int i = 1; i < 8; ++i) { u64 k2 = key[8 * j + i]; mn = k2 < mn ? k2 : mn; }
        gmin[j] = mn;
    }
    int* outp = g_knn + ((size_t)b * NQ + q) * KNN_;
    #pragma unroll 1
    for (int r = 0; r < KNN_; ++r) {
        u64 m01 = gmin[0] < gmin[1] ? gmin[0] : gmin[1];
        u64 m23 = gmin[2] < gmin[3] ? gmin[2] : gmin[3];
        u64 m   = m01 < m23 ? m01 : m23;
        #pragma unroll
        for (int off = 32; off >= 1; off >>= 1) {
            u64 o = __shfl_xor(m, off);
            m = o < m ? o : m;
        }
        if (lane == 0) outp[r] = (int)(m & 0x7FF);
        #pragma unroll
        for (int j = 0; j < 4; ++j) {
            if (gmin[j] == m) {
                u64 mn = ~0ULL;
                #pragma unroll
                for (int i = 0; i < 8; ++i) {
                    u64 k2 = key[8 * j + i];
                    k2 = (k2 == m) ? ~0ULL : k2;
                    key[8 * j + i] = k2;
                    mn = k2 < mn ? k2 : mn;
                }
                gmin[j] = mn;
            }
        }
    }
}

// ---------------------------------------------------------------------------
// Kernel B: per-batch q_attn, v_global, attn_g = MLP2(q_attn - k_global).
// ---------------------------------------------------------------------------
template<int BF16>
__global__ __launch_bounds__(256) void gtok_kernel(const void* __restrict__ lat,
    const void* __restrict__ Wq,  const void* __restrict__ Wkg, const void* __restrict__ Wvg,
    const void* __restrict__ Wg1, const void* __restrict__ bg1,
    const void* __restrict__ Wg2, const void* __restrict__ bg2)
{
    if (g_isbf16 != BF16) return;
    const int b = blockIdx.x, t = threadIdx.x;
    __shared__ float latS[DIM], xS[DIM], hS[DIM];
    latS[t] = ldf<BF16>(lat, (size_t)b * DIM + t);
    __syncthreads();
    float sq = 0.f, sk = 0.f, sv = 0.f;
    for (int i = 0; i < DIM; ++i) {
        float x = latS[i];
        sq += x * ldf<BF16>(Wq,  (size_t)t * DIM + i);
        sk += x * ldf<BF16>(Wkg, (size_t)t * DIM + i);
        sv += x * ldf<BF16>(Wvg, (size_t)t * DIM + i);
    }
    g_qattn[b * DIM + t] = sq;
    g_vglob[b * DIM + t] = sv;
    xS[t] = sq - sk;
    __syncthreads();
    float h = 0.f;
    for (int i = 0; i < DIM; ++i) h += xS[i] * ldf<BF16>(Wg1, (size_t)t * DIM + i);
    h += ldf<BF16>(bg1, t);
    hS[t] = fmaxf(h, 0.f);
    __syncthreads();
    float a = 0.f;
    for (int i = 0; i < DIM; ++i) a += hS[i] * ldf<BF16>(Wg2, (size_t)t * DIM + i);
    a += ldf<BF16>(bg2, t);
    g_attng[b * DIM + t] = a;
}

// ---------------------------------------------------------------------------
// Kernel C: fused attention. Block = 128 threads = 2 waves = 4 queries.
// Each wave owns 32 wave-private rows (2 row-tiles / 2 queries) -> every
// B-fragment load feeds 2 MFMAs (weight stream halved vs 1q/wave).
// vp = bf16(V+pos) lives in LDS (bufVP) -> no long-live-range registers,
// no spill. Single barrier (stage 0 broadcast) as in R6.
// ---------------------------------------------------------------------------
template<int BF16>
__global__ __launch_bounds__(128) void attn_kernel(
    const void* __restrict__ xyz_q, const void* __restrict__ xyz,
    const void* __restrict__ points,
    const void* __restrict__ Wd1, const void* __restrict__ bd1,
    const void* __restrict__ bd2, const void* __restrict__ bg1,
    const void* __restrict__ bg2,
    void* __restrict__ out)
{
    if (g_isbf16 != BF16) return;
    __shared__ u16 bufA[64 * DIM];               // 32 KB swizzled activations
    __shared__ u16 bufVP[64 * DIM];              // 32 KB vp = bf16(V+pos)
    __shared__ int nbrS[64];
    __shared__ float wd1S[DIM * 4];              // (w0,w1,w2,bd1) per output col
    __shared__ float qaS[DIM], agS[DIM], vgS[DIM];
    __shared__ float bd2S[DIM], bg1S[DIM], bg2S[DIM];

    const int b  = blockIdx.x >> 10;
    const int q0 = (blockIdx.x & 1023) << 2;
    const int t  = threadIdx.x;                  // 0..127

    // ---- stage 0: small shared data (the ONLY barrier-protected stage)
    for (int i = t; i < DIM; i += 128) {
        wd1S[i * 4 + 0] = ldf<BF16>(Wd1, (size_t)i * 3 + 0);
        wd1S[i * 4 + 1] = ldf<BF16>(Wd1, (size_t)i * 3 + 1);
        wd1S[i * 4 + 2] = ldf<BF16>(Wd1, (size_t)i * 3 + 2);
        wd1S[i * 4 + 3] = ldf<BF16>(bd1, i);
        bd2S[i] = ldf<BF16>(bd2, i);
        bg1S[i] = ldf<BF16>(bg1, i);
        bg2S[i] = ldf<BF16>(bg2, i);
        qaS[i] = g_qattn[b * DIM + i];
        agS[i] = g_attng[b * DIM + i];
        vgS[i] = g_vglob[b * DIM + i];
    }
    if (t < 64) {
        int qq = q0 + (t >> 4);
        nbrS[t] = g_knn[((size_t)b * NQ + qq) * KNN_ + (t & 15)];
    }
    __syncthreads();

    const int w = t >> 6, lane = t & 63;         // w in {0,1}
    const int rw2 = w << 5;                      // this wave's 32 rows
    const int q4 = lane >> 4, l15 = lane & 15;
    const int arow0 = rw2 + l15;
    const int arow1 = arow0 + 16;

    // packed-weight bases (fragment order): frag index = (ct*8+kt)*64 + lane
    const u16* WpD2 = g_wpack + 0 * DIM * DIM;
    const u16* WpK  = g_wpack + 1 * DIM * DIM;
    const u16* WpV  = g_wpack + 2 * DIM * DIM;
    const u16* WpG1 = g_wpack + 3 * DIM * DIM;
    const u16* WpG2 = g_wpack + 4 * DIM * DIM;

    // ---- gathered P-fragments for both tiles (issued early; die in stage 2)
    const size_t prow0 = ((size_t)b * NPT + nbrS[arow0]) * DIM;
    const size_t prow1 = ((size_t)b * NPT + nbrS[arow1]) * DIM;
    bf16x8 afrP0[8], afrP1[8];
    #pragma unroll
    for (int kt = 0; kt < 8; ++kt) {
        afrP0[kt] = ldfrag<BF16>(points, prow0 + ((((kt << 2) + q4)) << 3));
        afrP1[kt] = ldfrag<BF16>(points, prow1 + ((((kt << 2) + q4)) << 3));
    }

    // ---- stage 1: h1 = relu(d @ Wd1^T + bd1) -> bufA, wave-private 32 rows
    {
        const int rloc = lane >> 1;              // 0..31
        const int r    = rw2 + rloc;
        const int qv   = q0 + (r >> 4);
        const int n    = nbrS[r];
        const size_t nb3 = ((size_t)b * NPT + n) * 3;
        const size_t qb3 = ((size_t)b * NQ + qv) * 3;
        const float dx = ldf<BF16>(xyz_q, qb3 + 0) - ldf<BF16>(xyz, nb3 + 0);
        const float dy = ldf<BF16>(xyz_q, qb3 + 1) - ldf<BF16>(xyz, nb3 + 1);
        const float dz = ldf<BF16>(xyz_q, qb3 + 2) - ldf<BF16>(xyz, nb3 + 2);
        const int half = lane & 1;
        #pragma unroll
        for (int ci = 0; ci < 16; ++ci) {
            const int kc = (ci << 1) + half;
            u32 hw[4];
            #pragma unroll
            for (int pp = 0; pp < 4; ++pp) {
                const int c = (kc << 3) + pp * 2;
                const float* wv0 = wd1S + (size_t)c * 4;
                const float* wv1 = wd1S + (size_t)(c + 1) * 4;
                float h0 = wv0[0] * dx + wv0[1] * dy + wv0[2] * dz + wv0[3];
                float h1 = wv1[0] * dx + wv1[1] * dy + wv1[2] * dz + wv1[3];
                hw[pp] = (u32)f2bf(fmaxf(h0, 0.f)) | ((u32)f2bf(fmaxf(h1, 0.f)) << 16);
            }
            *(uint4*)(bufA + r * DIM + ((kc ^ (r & 7)) << 3)) = make_uint4(hw[0], hw[1], hw[2], hw[3]);
        }
    }
    // no barrier: rows are wave-private; in-wave LDS RAW handled by waitcnt

    // h1 fragments from LDS (both tiles)
    bf16x8 afrA0[8], afrA1[8];
    #pragma unroll
    for (int kt = 0; kt < 8; ++kt) {
        afrA0[kt] = *(const bf16x8*)(bufA + arow0 * DIM + ((((kt << 2) + q4) ^ (arow0 & 7)) << 3));
        afrA1[kt] = *(const bf16x8*)(bufA + arow1 * DIM + ((((kt << 2) + q4) ^ (arow1 & 7)) << 3));
    }

    // ---- stage 2: pos/K/V (both tiles); attn_in -> bufA; vp -> bufVP
    #pragma unroll 1
    for (int ct = 0; ct < 16; ++ct) {
        const int colg = (ct << 4) + l15;
        const int fbase = ((ct << 3) * 64 + lane) << 3;   // + kt*512 per kt
        f32x4 aP0 = {0.f,0.f,0.f,0.f}, aK0 = {0.f,0.f,0.f,0.f}, aV0 = {0.f,0.f,0.f,0.f};
        f32x4 aP1 = {0.f,0.f,0.f,0.f}, aK1 = {0.f,0.f,0.f,0.f}, aV1 = {0.f,0.f,0.f,0.f};
        #pragma unroll
        for (int kt = 0; kt < 8; ++kt) {
            const int fo = fbase + (kt << 9);
            bf16x8 bfrD = *(const bf16x8*)(WpD2 + fo);
            bf16x8 bfrK = *(const bf16x8*)(WpK  + fo);
            bf16x8 bfrV = *(const bf16x8*)(WpV  + fo);
            aP0 = __builtin_amdgcn_mfma_f32_16x16x32_bf16(afrA0[kt], bfrD, aP0, 0, 0, 0);
            aP1 = __builtin_amdgcn_mfma_f32_16x16x32_bf16(afrA1[kt], bfrD, aP1, 0, 0, 0);
            aK0 = __builtin_amdgcn_mfma_f32_16x16x32_bf16(afrP0[kt], bfrK, aK0, 0, 0, 0);
            aK1 = __builtin_amdgcn_mfma_f32_16x16x32_bf16(afrP1[kt], bfrK, aK1, 0, 0, 0);
            aV0 = __builtin_amdgcn_mfma_f32_16x16x32_bf16(afrP0[kt], bfrV, aV0, 0, 0, 0);
            aV1 = __builtin_amdgcn_mfma_f32_16x16x32_bf16(afrP1[kt], bfrV, aV1, 0, 0, 0);
        }
        const float bb = bd2S[colg];
        const float qa = qaS[colg];
        #pragma unroll
        for (int reg = 0; reg < 4; ++reg) {
            const float pv0 = aP0[reg] + bb;
            const float pv1 = aP1[reg] + bb;
            const int rr0 = rw2 + (q4 << 2) + reg;
            const int rr1 = rr0 + 16;
            bufA[swz(rr0, colg)]  = f2bf((qa - aK0[reg]) + pv0);
            bufA[swz(rr1, colg)]  = f2bf((qa - aK1[reg]) + pv1);
            bufVP[swz(rr0, colg)] = f2bf(aV0[reg] + pv0);
            bufVP[swz(rr1, colg)] = f2bf(aV1[reg] + pv1);
        }
    }

    // ---- stage 3: g1 = relu(attn_in@Wg1^T + bg1) -> bufA
    #pragma unroll
    for (int kt = 0; kt < 8; ++kt) {
        afrA0[kt] = *(const bf16x8*)(bufA + arow0 * DIM + ((((kt << 2) + q4) ^ (arow0 & 7)) << 3));
        afrA1[kt] = *(const bf16x8*)(bufA + arow1 * DIM + ((((kt << 2) + q4) ^ (arow1 & 7)) << 3));
    }
    #pragma unroll 1
    for (int ct = 0; ct < 16; ++ct) {
        const int colg = (ct << 4) + l15;
        const int fbase = ((ct << 3) * 64 + lane) << 3;
        f32x4 a0 = {0.f,0.f,0.f,0.f}, a1 = {0.f,0.f,0.f,0.f};
        #pragma unroll
        for (int kt = 0; kt < 8; ++kt) {
            bf16x8 bfr = *(const bf16x8*)(WpG1 + fbase + (kt << 9));
            a0 = __builtin_amdgcn_mfma_f32_16x16x32_bf16(afrA0[kt], bfr, a0, 0, 0, 0);
            a1 = __builtin_amdgcn_mfma_f32_16x16x32_bf16(afrA1[kt], bfr, a1, 0, 0, 0);
        }
        const float bb = bg1S[colg];
        #pragma unroll
        for (int reg = 0; reg < 4; ++reg) {
            bufA[swz(rw2      + (q4 << 2) + reg, colg)] = f2bf(fmaxf(a0[reg] + bb, 0.f));
            bufA[swz(rw2 + 16 + (q4 << 2) + reg, colg)] = f2bf(fmaxf(a1[reg] + bb, 0.f));
        }
    }

    // ---- stage 4: logits; softmax over 16 nbrs + global; output (2 queries)
    #pragma unroll
    for (int kt = 0; kt < 8; ++kt) {
        afrA0[kt] = *(const bf16x8*)(bufA + arow0 * DIM + ((((kt << 2) + q4) ^ (arow0 & 7)) << 3));
        afrA1[kt] = *(const bf16x8*)(bufA + arow1 * DIM + ((((kt << 2) + q4) ^ (arow1 & 7)) << 3));
    }
    const int qA = q0 + (w << 1);
    const size_t outqA = ((size_t)b * NQ + qA) * DIM;
    const size_t outqB = outqA + DIM;
    #pragma unroll 1
    for (int ct = 0; ct < 16; ++ct) {
        const int colg = (ct << 4) + l15;
        const int fbase = ((ct << 3) * 64 + lane) << 3;
        f32x4 aL0 = {0.f,0.f,0.f,0.f}, aL1 = {0.f,0.f,0.f,0.f};
        #pragma unroll
        for (int kt = 0; kt < 8; ++kt) {
            bf16x8 bfrG = *(const bf16x8*)(WpG2 + fbase + (kt << 9));
            aL0 = __builtin_amdgcn_mfma_f32_16x16x32_bf16(afrA0[kt], bfrG, aL0, 0, 0, 0);
            aL1 = __builtin_amdgcn_mfma_f32_16x16x32_bf16(afrA1[kt], bfrG, aL1, 0, 0, 0);
        }
        const float bb = bg2S[colg];
        const float gl = fminf(30.f, fmaxf(-30.f, agS[colg]));
        const float vg = vgS[colg];
        #pragma unroll
        for (int tt = 0; tt < 2; ++tt) {
            const f32x4& aL = tt ? aL1 : aL0;
            const int rr = rw2 + (tt << 4) + (q4 << 2);
            const float l0 = fminf(30.f, fmaxf(-30.f, aL[0] + bb));
            const float l1 = fminf(30.f, fmaxf(-30.f, aL[1] + bb));
            const float l2 = fminf(30.f, fmaxf(-30.f, aL[2] + bb));
            const float l3 = fminf(30.f, fmaxf(-30.f, aL[3] + bb));
            float mx = fmaxf(fmaxf(l0, l1), fmaxf(l2, l3));
            mx = fmaxf(mx, __shfl_xor(mx, 16));
            mx = fmaxf(mx, __shfl_xor(mx, 32));
            mx = fmaxf(mx, gl);
            const float e0 = expf(l0 - mx), e1 = expf(l1 - mx);
            const float e2 = expf(l2 - mx), e3 = expf(l3 - mx);
            float s = (e0 + e1) + (e2 + e3);
            s += __shfl_xor(s, 16);
            s += __shfl_xor(s, 32);
            const float eg  = expf(gl - mx);
            const float inv = 1.0f / (s + eg);
            float o = e0 * bf2f(bufVP[swz(rr + 0, colg)])
                    + e1 * bf2f(bufVP[swz(rr + 1, colg)])
                    + e2 * bf2f(bufVP[swz(rr + 2, colg)])
                    + e3 * bf2f(bufVP[swz(rr + 3, colg)]);
            o += __shfl_xor(o, 16);
            o += __shfl_xor(o, 32);
            o = (o + eg * vg) * inv;
            if (lane < 16) {
                const size_t oq = tt ? outqB : outqA;
                if (BF16) ((u16*)out)[oq + colg] = f2bf(o);
                else      ((float*)out)[oq + colg] = o;
            }
        }
    }
}

// ---------------------------------------------------------------------------
extern "C" void kernel_launch(void* const* d_in, const int* in_sizes, int n_in,
                              void* d_out, int out_size, void* d_ws, size_t ws_size,
                              hipStream_t stream)
{
    const void* xyz_q  = d_in[0];
    const void* lat    = d_in[1];
    const void* xyz    = d_in[2];
    const void* points = d_in[3];
    const void* Wd1 = d_in[4];
    const void* bd1 = d_in[5];
    const void* Wd2 = d_in[6];
    const void* bd2 = d_in[7];
    const void* Wg1 = d_in[8];
    const void* bg1 = d_in[9];
    const void* Wg2 = d_in[10];
    const void* bg2 = d_in[11];
    const void* Wkg = d_in[12];
    const void* Wvg = d_in[13];
    const void* Wq  = d_in[14];
    const void* Wk  = d_in[15];
    const void* Wv  = d_in[16];

    probe_kernel<<<1, 64, 0, stream>>>((const u32*)lat);

    repack_kernel<1><<<dim3(32, 5), 256, 0, stream>>>(Wd2, Wk, Wv, Wg1, Wg2);
    repack_kernel<0><<<dim3(32, 5), 256, 0, stream>>>(Wd2, Wk, Wv, Wg1, Wg2);
    knn_kernel<1><<<4096, 256, 0, stream>>>(xyz_q, xyz);
    knn_kernel<0><<<4096, 256, 0, stream>>>(xyz_q, xyz);
    gtok_kernel<1><<<4, 256, 0, stream>>>(lat, Wq, Wkg, Wvg, Wg1, bg1, Wg2, bg2);
    gtok_kernel<0><<<4, 256, 0, stream>>>(lat, Wq, Wkg, Wvg, Wg1, bg1, Wg2, bg2);
    attn_kernel<1><<<4096, 128, 0, stream>>>(xyz_q, xyz, points,
                                             Wd1, bd1, bd2, bg1, bg2, d_out);
    attn_kernel<0><<<4096, 128, 0, stream>>>(xyz_q, xyz, points,
                                             Wd1, bd1, bd2, bg1, bg2, d_out);
}

// Round 9
// 518.625 us; speedup vs baseline: 1.8673x; 1.3607x over previous
//
#include <hip/hip_runtime.h>
#include <stdint.h>
#include <math.h>

typedef unsigned short u16;
typedef unsigned int   u32;
typedef unsigned long long u64;
typedef __attribute__((ext_vector_type(8))) short bf16x8;
typedef __attribute__((ext_vector_type(4))) float f32x4;

#define NB   4
#define NQ   4096
#define NPT  2048
#define DIM  256
#define KNN_ 16

// ---------------- module-global scratch (no d_ws dependence) ----------------
__device__ int   g_isbf16;
__device__ int   g_knn[NB * NQ * KNN_];        // 1 MB
__device__ float g_qattn[NB * DIM];
__device__ float g_vglob[NB * DIM];
__device__ float g_attng[NB * DIM];
// fragment-ordered packed weights: [mat][ct][kt][lane][8] ; mats: Wd2,Wk,Wv,Wg1,Wg2
__device__ u16   g_wpack[5 * DIM * DIM];       // 640 KB
__device__ u16   g_kmat[NB * NPT * DIM];       // 4 MB  K = points @ Wk^T
__device__ u16   g_vmat[NB * NPT * DIM];       // 4 MB  V = points @ Wv^T

__device__ __forceinline__ float bf2f(u16 u) {
    union { u32 i; float f; } v; v.i = ((u32)u) << 16; return v.f;
}
__device__ __forceinline__ u16 f2bf(float f) {
    union { float f; u32 i; } v; v.f = f;
    u32 u = v.i;
    return (u16)((u + 0x7FFFu + ((u >> 16) & 1u)) >> 16);
}
// dtype-agnostic scalar load
template<int BF16>
__device__ __forceinline__ float ldf(const void* p, size_t i) {
    if (BF16) return bf2f(((const u16*)p)[i]);
    return ((const float*)p)[i];
}
// dtype-agnostic 8-element fragment load -> bf16x8 (16B-aligned in both modes)
template<int BF16>
__device__ __forceinline__ bf16x8 ldfrag(const void* p, size_t i) {
    if (BF16) return *(const bf16x8*)((const u16*)p + i);
    const float* f = (const float*)p + i;
    float4 a = *(const float4*)f;
    float4 b = *(const float4*)(f + 4);
    bf16x8 r;
    r[0] = (short)f2bf(a.x); r[1] = (short)f2bf(a.y);
    r[2] = (short)f2bf(a.z); r[3] = (short)f2bf(a.w);
    r[4] = (short)f2bf(b.x); r[5] = (short)f2bf(b.y);
    r[6] = (short)f2bf(b.z); r[7] = (short)f2bf(b.w);
    return r;
}
// XOR-swizzled element address inside a [rows][256] bf16 LDS tile
__device__ __forceinline__ int swz(int r, int c) {
    return r * DIM + ((((c >> 3) ^ (r & 7))) << 3) + (c & 7);
}

// ---------------------------------------------------------------------------
// Probe: classify input dtype from lat_rep bit patterns.
// ---------------------------------------------------------------------------
__global__ void probe_kernel(const u32* __restrict__ lat)
{
    if (threadIdx.x == 0 && blockIdx.x == 0) {
        int cnt = 0;
        for (int i = 0; i < 64; ++i) {
            u32 e = (lat[i] >> 7) & 0xFF;
            cnt += (e >= 110 && e <= 133) ? 1 : 0;
        }
        g_isbf16 = (cnt >= 32) ? 1 : 0;
    }
}

// ---------------------------------------------------------------------------
// Repack the 5 hot weight matrices into MFMA-fragment order:
// dst[(((ct*8+kt)*4+q4)*16+l15)*8 + j] = W[ct*16+l15][kt*32+q4*8+j]
// ---------------------------------------------------------------------------
template<int BF16>
__global__ __launch_bounds__(256) void repack_kernel(
    const void* __restrict__ Wd2, const void* __restrict__ Wk,
    const void* __restrict__ Wv,  const void* __restrict__ Wg1,
    const void* __restrict__ Wg2)
{
    if (g_isbf16 != BF16) return;
    const void* srcs[5] = { Wd2, Wk, Wv, Wg1, Wg2 };
    const int m   = blockIdx.y;
    const int tid = blockIdx.x * 256 + threadIdx.x;   // 0..8191
    const int ct  = tid >> 9;
    const int kt  = (tid >> 6) & 7;
    const int q4  = (tid >> 4) & 3;
    const int l15 = tid & 15;
    const int row = ct * 16 + l15;
    const int col = (kt << 5) + (q4 << 3);
    bf16x8 v = ldfrag<BF16>(srcs[m], (size_t)row * DIM + col);
    *(bf16x8*)(g_wpack + m * DIM * DIM + (tid << 3)) = v;
}

// ---------------------------------------------------------------------------
// Proj: K = points@Wk^T, V = points@Wv^T once per point (2048x4 rows).
// Block = 64 rows, 4 waves; uses packed WpK/WpV fragments (contiguous loads).
// ---------------------------------------------------------------------------
template<int BF16>
__global__ __launch_bounds__(256) void proj_kernel(const void* __restrict__ points)
{
    if (g_isbf16 != BF16) return;
    __shared__ u16 bufP[64 * DIM];               // 32 KB swizzled points tile
    const int rb = blockIdx.x;                   // 0..31
    const int b  = blockIdx.y;                   // 0..3
    const int t  = threadIdx.x;
    const int r0 = rb * 64;
    for (int cc = t; cc < 64 * 32; cc += 256) {
        int r = cc >> 5, kc = cc & 31;
        bf16x8 v = ldfrag<BF16>(points, ((size_t)b * NPT + r0 + r) * DIM + (kc << 3));
        *(bf16x8*)(bufP + r * DIM + ((kc ^ (r & 7)) << 3)) = v;
    }
    __syncthreads();
    const int w = t >> 6, lane = t & 63;
    const int rw = w << 4;
    const int q4 = lane >> 4, l15 = lane & 15;
    const int arow = rw + l15;
    bf16x8 afr[8];
    #pragma unroll
    for (int kt = 0; kt < 8; ++kt)
        afr[kt] = *(const bf16x8*)(bufP + arow * DIM + ((((kt << 2) + q4) ^ (arow & 7)) << 3));
    const u16* WpK = g_wpack + 1 * DIM * DIM;
    const u16* WpV = g_wpack + 2 * DIM * DIM;
    #pragma unroll 1
    for (int ct = 0; ct < 16; ++ct) {
        const int colg = (ct << 4) + l15;
        const int fbase = ((ct << 3) * 64 + lane) << 3;
        f32x4 accK = {0.f,0.f,0.f,0.f}, accV = {0.f,0.f,0.f,0.f};
        #pragma unroll
        for (int kt = 0; kt < 8; ++kt) {
            bf16x8 bfrK = *(const bf16x8*)(WpK + fbase + (kt << 9));
            bf16x8 bfrV = *(const bf16x8*)(WpV + fbase + (kt << 9));
            accK = __builtin_amdgcn_mfma_f32_16x16x32_bf16(afr[kt], bfrK, accK, 0, 0, 0);
            accV = __builtin_amdgcn_mfma_f32_16x16x32_bf16(afr[kt], bfrV, accV, 0, 0, 0);
        }
        #pragma unroll
        for (int reg = 0; reg < 4; ++reg) {
            const int rr = r0 + rw + (q4 << 2) + reg;
            g_kmat[((size_t)b * NPT + rr) * DIM + colg] = f2bf(accK[reg]);
            g_vmat[((size_t)b * NPT + rr) * DIM + colg] = f2bf(accV[reg]);
        }
    }
}

// ---------------------------------------------------------------------------
// Kernel A: exact 16-NN per query. f64 distances, index in low mantissa bits.
// ---------------------------------------------------------------------------
template<int BF16>
__global__ __launch_bounds__(256) void knn_kernel(const void* __restrict__ xyz_q,
                                                  const void* __restrict__ xyz)
{
    if (g_isbf16 != BF16) return;
    __shared__ float4 pts[NPT];                  // 32 KB
    const int b  = blockIdx.x >> 10;
    const int q0 = (blockIdx.x & 1023) << 2;
    const int t  = threadIdx.x;
    for (int i = t; i < NPT; i += 256) {
        const size_t base = ((size_t)b * NPT + i) * 3;
        pts[i] = make_float4(ldf<BF16>(xyz, base + 0),
                             ldf<BF16>(xyz, base + 1),
                             ldf<BF16>(xyz, base + 2), 0.f);
    }
    __syncthreads();

    const int w = t >> 6, lane = t & 63;
    const int q = q0 + w;
    const size_t qb = ((size_t)b * NQ + q) * 3;
    const double qx = (double)ldf<BF16>(xyz_q, qb + 0);
    const double qy = (double)ldf<BF16>(xyz_q, qb + 1);
    const double qz = (double)ldf<BF16>(xyz_q, qb + 2);

    u64 key[32];
    #pragma unroll
    for (int i = 0; i < 32; ++i) {
        const int n = (i << 6) + lane;
        float4 p = pts[n];
        double dx = qx - (double)p.x;
        double dy = qy - (double)p.y;
        double dz = qz - (double)p.z;
        double d2 = fma(dx, dx, fma(dy, dy, dz * dz));   // >= 0
        key[i] = (((u64)__double_as_longlong(d2)) & 0xFFFFFFFFFFFFF800ULL) | (u64)n;
    }
    u64 gmin[4];
    #pragma unroll
    for (int j = 0; j < 4; ++j) {
        u64 mn = key[8 * j];
        #pragma unroll
        for (int i = 1; i < 8; ++i) { u64 k2 = key[8 * j + i]; mn = k2 < mn ? k2 : mn; }
        gmin[j] = mn;
    }
    int* outp = g_knn + ((size_t)b * NQ + q) * KNN_;
    #pragma unroll 1
    for (int r = 0; r < KNN_; ++r) {
        u64 m01 = gmin[0] < gmin[1] ? gmin[0] : gmin[1];
        u64 m23 = gmin[2] < gmin[3] ? gmin[2] : gmin[3];
        u64 m   = m01 < m23 ? m01 : m23;
        #pragma unroll
        for (int off = 32; off >= 1; off >>= 1) {
            u64 o = __shfl_xor(m, off);
            m = o < m ? o : m;
        }
        if (lane == 0) outp[r] = (int)(m & 0x7FF);
        #pragma unroll
        for (int j = 0; j < 4; ++j) {
            if (gmin[j] == m) {
                u64 mn = ~0ULL;
                #pragma unroll
                for (int i = 0; i < 8; ++i) {
                    u64 k2 = key[8 * j + i];
                    k2 = (k2 == m) ? ~0ULL : k2;
                    key[8 * j + i] = k2;
                    mn = k2 < mn ? k2 : mn;
                }
                gmin[j] = mn;
            }
        }
    }
}

// ---------------------------------------------------------------------------
// Kernel B: per-batch q_attn, v_global, attn_g = MLP2(q_attn - k_global).
// ---------------------------------------------------------------------------
template<int BF16>
__global__ __launch_bounds__(256) void gtok_kernel(const void* __restrict__ lat,
    const void* __restrict__ Wq,  const void* __restrict__ Wkg, const void* __restrict__ Wvg,
    const void* __restrict__ Wg1, const void* __restrict__ bg1,
    const void* __restrict__ Wg2, const void* __restrict__ bg2)
{
    if (g_isbf16 != BF16) return;
    const int b = blockIdx.x, t = threadIdx.x;
    __shared__ float latS[DIM], xS[DIM], hS[DIM];
    latS[t] = ldf<BF16>(lat, (size_t)b * DIM + t);
    __syncthreads();
    float sq = 0.f, sk = 0.f, sv = 0.f;
    for (int i = 0; i < DIM; ++i) {
        float x = latS[i];
        sq += x * ldf<BF16>(Wq,  (size_t)t * DIM + i);
        sk += x * ldf<BF16>(Wkg, (size_t)t * DIM + i);
        sv += x * ldf<BF16>(Wvg, (size_t)t * DIM + i);
    }
    g_qattn[b * DIM + t] = sq;
    g_vglob[b * DIM + t] = sv;
    xS[t] = sq - sk;
    __syncthreads();
    float h = 0.f;
    for (int i = 0; i < DIM; ++i) h += xS[i] * ldf<BF16>(Wg1, (size_t)t * DIM + i);
    h += ldf<BF16>(bg1, t);
    hS[t] = fmaxf(h, 0.f);
    __syncthreads();
    float a = 0.f;
    for (int i = 0; i < DIM; ++i) a += hS[i] * ldf<BF16>(Wg2, (size_t)t * DIM + i);
    a += ldf<BF16>(bg2, t);
    g_attng[b * DIM + t] = a;
}

// ---------------------------------------------------------------------------
// Kernel C: fused attention. Block = 256 thr = 4 waves = 4 queries = 64 rows
// (R6 shape: 2 blocks/CU, 8 waves/CU). K/V PRECOMPUTED (g_kmat/g_vmat):
// stage 2 is now a single pos-matmul; K/V rows gathered once per wave into
// bufA (over consumed h1) / bufVP, then element-wise RMW per ct.
// ---------------------------------------------------------------------------
template<int BF16>
__global__ __launch_bounds__(256) void attn_kernel(
    const void* __restrict__ xyz_q, const void* __restrict__ xyz,
    const void* __restrict__ Wd1, const void* __restrict__ bd1,
    const void* __restrict__ bd2, const void* __restrict__ bg1,
    const void* __restrict__ bg2,
    void* __restrict__ out)
{
    if (g_isbf16 != BF16) return;
    __shared__ u16 bufA[64 * DIM];               // 32 KB: h1 -> K -> attn_in -> g1
    __shared__ u16 bufVP[64 * DIM];              // 32 KB: V -> vp = bf16(V+pos)
    __shared__ int nbrS[64];
    __shared__ float wd1S[DIM * 4];              // (w0,w1,w2,bd1) per output col
    __shared__ float qaS[DIM], agS[DIM], vgS[DIM];
    __shared__ float bd2S[DIM], bg1S[DIM], bg2S[DIM];

    const int b  = blockIdx.x >> 10;
    const int q0 = (blockIdx.x & 1023) << 2;
    const int t  = threadIdx.x;

    // ---- stage 0: small shared data (the ONLY barrier-protected stage)
    wd1S[t * 4 + 0] = ldf<BF16>(Wd1, (size_t)t * 3 + 0);
    wd1S[t * 4 + 1] = ldf<BF16>(Wd1, (size_t)t * 3 + 1);
    wd1S[t * 4 + 2] = ldf<BF16>(Wd1, (size_t)t * 3 + 2);
    wd1S[t * 4 + 3] = ldf<BF16>(bd1, t);
    bd2S[t] = ldf<BF16>(bd2, t);
    bg1S[t] = ldf<BF16>(bg1, t);
    bg2S[t] = ldf<BF16>(bg2, t);
    qaS[t] = g_qattn[b * DIM + t];
    agS[t] = g_attng[b * DIM + t];
    vgS[t] = g_vglob[b * DIM + t];
    if (t < 64) {
        int qq = q0 + (t >> 4);
        nbrS[t] = g_knn[((size_t)b * NQ + qq) * KNN_ + (t & 15)];
    }
    __syncthreads();

    const int w = t >> 6, lane = t & 63;
    const int q  = q0 + w;                       // one query per wave
    const int rw = w << 4;                       // this wave's 16 rows
    const int q4 = lane >> 4, l15 = lane & 15;
    const int arow = rw + l15;

    // packed-weight bases (fragment order): frag index = (ct*8+kt)*64 + lane
    const u16* WpD2 = g_wpack + 0 * DIM * DIM;
    const u16* WpG1 = g_wpack + 3 * DIM * DIM;
    const u16* WpG2 = g_wpack + 4 * DIM * DIM;

    // ---- stage 1: h1 = relu(d @ Wd1^T + bd1) -> bufA, wave-private rows
    {
        const int r = rw + (lane >> 2);
        const int n = nbrS[r];
        const size_t nb3 = ((size_t)b * NPT + n) * 3;
        const size_t qb3 = ((size_t)b * NQ  + q) * 3;
        const float dx = ldf<BF16>(xyz_q, qb3 + 0) - ldf<BF16>(xyz, nb3 + 0);
        const float dy = ldf<BF16>(xyz_q, qb3 + 1) - ldf<BF16>(xyz, nb3 + 1);
        const float dz = ldf<BF16>(xyz_q, qb3 + 2) - ldf<BF16>(xyz, nb3 + 2);
        #pragma unroll
        for (int ci = 0; ci < 8; ++ci) {
            const int kc = (lane & 3) + (ci << 2);
            u32 hw[4];
            #pragma unroll
            for (int pp = 0; pp < 4; ++pp) {
                const int c = (kc << 3) + pp * 2;
                const float* wv0 = wd1S + (size_t)c * 4;
                const float* wv1 = wd1S + (size_t)(c + 1) * 4;
                float h0 = wv0[0] * dx + wv0[1] * dy + wv0[2] * dz + wv0[3];
                float h1 = wv1[0] * dx + wv1[1] * dy + wv1[2] * dz + wv1[3];
                hw[pp] = (u32)f2bf(fmaxf(h0, 0.f)) | ((u32)f2bf(fmaxf(h1, 0.f)) << 16);
            }
            *(uint4*)(bufA + r * DIM + ((kc ^ (r & 7)) << 3)) = make_uint4(hw[0], hw[1], hw[2], hw[3]);
        }
    }
    // no barrier: rows are wave-private; in-wave LDS ordering via lgkmcnt

    // h1 fragments from LDS (consumes bufA h1)
    bf16x8 afrA[8];
    #pragma unroll
    for (int kt = 0; kt < 8; ++kt)
        afrA[kt] = *(const bf16x8*)(bufA + arow * DIM + ((((kt << 2) + q4) ^ (arow & 7)) << 3));

    // ---- stage K/V: gather this wave's 16 neighbor rows of precomputed
    //      K into bufA (overwriting consumed h1 — DS pipe is in-order per
    //      wave, so the afrA reads above complete first) and V into bufVP.
    {
        const int r = rw + (lane >> 2);
        const size_t kvb = ((size_t)b * NPT + nbrS[r]) * DIM;
        #pragma unroll
        for (int ci = 0; ci < 8; ++ci) {
            const int kc = (lane & 3) + (ci << 2);
            bf16x8 kv = *(const bf16x8*)(g_kmat + kvb + (kc << 3));
            bf16x8 vv = *(const bf16x8*)(g_vmat + kvb + (kc << 3));
            *(bf16x8*)(bufA  + r * DIM + ((kc ^ (r & 7)) << 3)) = kv;
            *(bf16x8*)(bufVP + r * DIM + ((kc ^ (r & 7)) << 3)) = vv;
        }
    }

    // ---- stage 2: pos = h1@Wd2^T + bd2 (single matmul);
    //      attn_in = (qa - K) + pos -> bufA (in-place over K);
    //      vp = bf16(V + pos)      -> bufVP (in-place over V).
    #pragma unroll 1
    for (int ct = 0; ct < 16; ++ct) {
        const int colg = (ct << 4) + l15;
        const int fbase = ((ct << 3) * 64 + lane) << 3;   // + kt*512 per kt
        f32x4 aP = {0.f,0.f,0.f,0.f};
        #pragma unroll
        for (int kt = 0; kt < 8; ++kt) {
            bf16x8 bfrD = *(const bf16x8*)(WpD2 + fbase + (kt << 9));
            aP = __builtin_amdgcn_mfma_f32_16x16x32_bf16(afrA[kt], bfrD, aP, 0, 0, 0);
        }
        const float bb = bd2S[colg];
        const float qa = qaS[colg];
        #pragma unroll
        for (int reg = 0; reg < 4; ++reg) {
            const int rr = rw + (q4 << 2) + reg;
            const int ad = swz(rr, colg);
            const float pv = aP[reg] + bb;
            const float kv = bf2f(bufA[ad]);
            const float vv = bf2f(bufVP[ad]);
            bufA[ad]  = f2bf((qa - kv) + pv);
            bufVP[ad] = f2bf(vv + pv);
        }
    }

    // ---- stage 3: g1 = relu(attn_in@Wg1^T + bg1) -> bufA
    #pragma unroll
    for (int kt = 0; kt < 8; ++kt)
        afrA[kt] = *(const bf16x8*)(bufA + arow * DIM + ((((kt << 2) + q4) ^ (arow & 7)) << 3));
    #pragma unroll 1
    for (int ct = 0; ct < 16; ++ct) {
        const int colg = (ct << 4) + l15;
        const int fbase = ((ct << 3) * 64 + lane) << 3;
        f32x4 acc = {0.f,0.f,0.f,0.f};
        #pragma unroll
        for (int kt = 0; kt < 8; ++kt) {
            bf16x8 bfr = *(const bf16x8*)(WpG1 + fbase + (kt << 9));
            acc = __builtin_amdgcn_mfma_f32_16x16x32_bf16(afrA[kt], bfr, acc, 0, 0, 0);
        }
        const float bb = bg1S[colg];
        #pragma unroll
        for (int reg = 0; reg < 4; ++reg) {
            const int rr = rw + (q4 << 2) + reg;
            bufA[swz(rr, colg)] = f2bf(fmaxf(acc[reg] + bb, 0.f));
        }
    }

    // ---- stage 4: logits = g1@Wg2^T + bg2; softmax over 16 nbrs + global;
    //               out = sum_j w_j * vp_j + w_g * v_global
    #pragma unroll
    for (int kt = 0; kt < 8; ++kt)
        afrA[kt] = *(const bf16x8*)(bufA + arow * DIM + ((((kt << 2) + q4) ^ (arow & 7)) << 3));
    const size_t outq = ((size_t)b * NQ + q) * DIM;
    #pragma unroll 1
    for (int ct = 0; ct < 16; ++ct) {
        const int colg = (ct << 4) + l15;
        const int fbase = ((ct << 3) * 64 + lane) << 3;
        f32x4 accL = {0.f,0.f,0.f,0.f};
        #pragma unroll
        for (int kt = 0; kt < 8; ++kt) {
            bf16x8 bfrG = *(const bf16x8*)(WpG2 + fbase + (kt << 9));
            accL = __builtin_amdgcn_mfma_f32_16x16x32_bf16(afrA[kt], bfrG, accL, 0, 0, 0);
        }
        const float bb = bg2S[colg];
        const float l0 = fminf(30.f, fmaxf(-30.f, accL[0] + bb));
        const float l1 = fminf(30.f, fmaxf(-30.f, accL[1] + bb));
        const float l2 = fminf(30.f, fmaxf(-30.f, accL[2] + bb));
        const float l3 = fminf(30.f, fmaxf(-30.f, accL[3] + bb));
        const float gl = fminf(30.f, fmaxf(-30.f, agS[colg]));
        float mx = fmaxf(fmaxf(l0, l1), fmaxf(l2, l3));
        mx = fmaxf(mx, __shfl_xor(mx, 16));
        mx = fmaxf(mx, __shfl_xor(mx, 32));
        mx = fmaxf(mx, gl);
        const float e0 = expf(l0 - mx), e1 = expf(l1 - mx);
        const float e2 = expf(l2 - mx), e3 = expf(l3 - mx);
        float s = (e0 + e1) + (e2 + e3);
        s += __shfl_xor(s, 16);
        s += __shfl_xor(s, 32);
        const float eg  = expf(gl - mx);
        const float inv = 1.0f / (s + eg);
        const int rr = rw + (q4 << 2);
        float o = e0 * bf2f(bufVP[swz(rr + 0, colg)])
                + e1 * bf2f(bufVP[swz(rr + 1, colg)])
                + e2 * bf2f(bufVP[swz(rr + 2, colg)])
                + e3 * bf2f(bufVP[swz(rr + 3, colg)]);
        o += __shfl_xor(o, 16);
        o += __shfl_xor(o, 32);
        o = (o + eg * vgS[colg]) * inv;
        if (lane < 16) {
            if (BF16) ((u16*)out)[outq + colg] = f2bf(o);
            else      ((float*)out)[outq + colg] = o;
        }
    }
}

// ---------------------------------------------------------------------------
extern "C" void kernel_launch(void* const* d_in, const int* in_sizes, int n_in,
                              void* d_out, int out_size, void* d_ws, size_t ws_size,
                              hipStream_t stream)
{
    const void* xyz_q  = d_in[0];
    const void* lat    = d_in[1];
    const void* xyz    = d_in[2];
    const void* points = d_in[3];
    const void* Wd1 = d_in[4];
    const void* bd1 = d_in[5];
    const void* Wd2 = d_in[6];
    const void* bd2 = d_in[7];
    const void* Wg1 = d_in[8];
    const void* bg1 = d_in[9];
    const void* Wg2 = d_in[10];
    const void* bg2 = d_in[11];
    const void* Wkg = d_in[12];
    const void* Wvg = d_in[13];
    const void* Wq  = d_in[14];
    const void* Wk  = d_in[15];
    const void* Wv  = d_in[16];

    probe_kernel<<<1, 64, 0, stream>>>((const u32*)lat);

    repack_kernel<1><<<dim3(32, 5), 256, 0, stream>>>(Wd2, Wk, Wv, Wg1, Wg2);
    repack_kernel<0><<<dim3(32, 5), 256, 0, stream>>>(Wd2, Wk, Wv, Wg1, Wg2);
    proj_kernel<1><<<dim3(32, 4), 256, 0, stream>>>(points);
    proj_kernel<0><<<dim3(32, 4), 256, 0, stream>>>(points);
    knn_kernel<1><<<4096, 256, 0, stream>>>(xyz_q, xyz);
    knn_kernel<0><<<4096, 256, 0, stream>>>(xyz_q, xyz);
    gtok_kernel<1><<<4, 256, 0, stream>>>(lat, Wq, Wkg, Wvg, Wg1, bg1, Wg2, bg2);
    gtok_kernel<0><<<4, 256, 0, stream>>>(lat, Wq, Wkg, Wvg, Wg1, bg1, Wg2, bg2);
    attn_kernel<1><<<4096, 256, 0, stream>>>(xyz_q, xyz,
                                             Wd1, bd1, bd2, bg1, bg2, d_out);
    attn_kernel<0><<<4096, 256, 0, stream>>>(xyz_q, xyz,
                                             Wd1, bd1, bd2, bg1, bg2, d_out);
}

// Round 10
// 497.166 us; speedup vs baseline: 1.9479x; 1.0432x over previous
//
#include <hip/hip_runtime.h>
#include <stdint.h>
#include <math.h>

typedef unsigned short u16;
typedef unsigned int   u32;
typedef unsigned long long u64;
typedef __attribute__((ext_vector_type(8))) short bf16x8;
typedef __attribute__((ext_vector_type(4))) float f32x4;

#define NB   4
#define NQ   4096
#define NPT  2048
#define DIM  256
#define KNN_ 16

// ---------------- module-global scratch (no d_ws dependence) ----------------
__device__ int   g_isbf16;
__device__ int   g_knn[NB * NQ * KNN_];        // 1 MB
__device__ float g_qattn[NB * DIM];
__device__ float g_vglob[NB * DIM];
__device__ float g_attng[NB * DIM];
// fragment-ordered packed weights: [mat][ct][kt][lane][8] ; mats: Wd2,Wk,Wv,Wg1,Wg2
__device__ u16   g_wpack[5 * DIM * DIM];       // 640 KB
__device__ u16   g_kmat[NB * NPT * DIM];       // 4 MB  K = points @ Wk^T
__device__ u16   g_vmat[NB * NPT * DIM];       // 4 MB  V = points @ Wv^T

__device__ __forceinline__ float bf2f(u16 u) {
    union { u32 i; float f; } v; v.i = ((u32)u) << 16; return v.f;
}
__device__ __forceinline__ u16 f2bf(float f) {
    union { float f; u32 i; } v; v.f = f;
    u32 u = v.i;
    return (u16)((u + 0x7FFFu + ((u >> 16) & 1u)) >> 16);
}
// dtype-agnostic scalar load
template<int BF16>
__device__ __forceinline__ float ldf(const void* p, size_t i) {
    if (BF16) return bf2f(((const u16*)p)[i]);
    return ((const float*)p)[i];
}
// dtype-agnostic 8-element fragment load -> bf16x8 (16B-aligned in both modes)
template<int BF16>
__device__ __forceinline__ bf16x8 ldfrag(const void* p, size_t i) {
    if (BF16) return *(const bf16x8*)((const u16*)p + i);
    const float* f = (const float*)p + i;
    float4 a = *(const float4*)f;
    float4 b = *(const float4*)(f + 4);
    bf16x8 r;
    r[0] = (short)f2bf(a.x); r[1] = (short)f2bf(a.y);
    r[2] = (short)f2bf(a.z); r[3] = (short)f2bf(a.w);
    r[4] = (short)f2bf(b.x); r[5] = (short)f2bf(b.y);
    r[6] = (short)f2bf(b.z); r[7] = (short)f2bf(b.w);
    return r;
}
// XOR-swizzled element address inside a [rows][256] bf16 LDS tile
__device__ __forceinline__ int swz(int r, int c) {
    return r * DIM + ((((c >> 3) ^ (r & 7))) << 3) + (c & 7);
}

// ---------------------------------------------------------------------------
// Probe: classify input dtype from lat_rep bit patterns.
// ---------------------------------------------------------------------------
__global__ void probe_kernel(const u32* __restrict__ lat)
{
    if (threadIdx.x == 0 && blockIdx.x == 0) {
        int cnt = 0;
        for (int i = 0; i < 64; ++i) {
            u32 e = (lat[i] >> 7) & 0xFF;
            cnt += (e >= 110 && e <= 133) ? 1 : 0;
        }
        g_isbf16 = (cnt >= 32) ? 1 : 0;
    }
}

// ---------------------------------------------------------------------------
// Repack the 5 hot weight matrices into MFMA-fragment order:
// dst[(((ct*8+kt)*4+q4)*16+l15)*8 + j] = W[ct*16+l15][kt*32+q4*8+j]
// ---------------------------------------------------------------------------
template<int BF16>
__global__ __launch_bounds__(256) void repack_kernel(
    const void* __restrict__ Wd2, const void* __restrict__ Wk,
    const void* __restrict__ Wv,  const void* __restrict__ Wg1,
    const void* __restrict__ Wg2)
{
    if (g_isbf16 != BF16) return;
    const void* srcs[5] = { Wd2, Wk, Wv, Wg1, Wg2 };
    const int m   = blockIdx.y;
    const int tid = blockIdx.x * 256 + threadIdx.x;   // 0..8191
    const int ct  = tid >> 9;
    const int kt  = (tid >> 6) & 7;
    const int q4  = (tid >> 4) & 3;
    const int l15 = tid & 15;
    const int row = ct * 16 + l15;
    const int col = (kt << 5) + (q4 << 3);
    bf16x8 v = ldfrag<BF16>(srcs[m], (size_t)row * DIM + col);
    *(bf16x8*)(g_wpack + m * DIM * DIM + (tid << 3)) = v;
}

// ---------------------------------------------------------------------------
// Proj: K = points@Wk^T, V = points@Wv^T once per point (2048x4 rows).
// ---------------------------------------------------------------------------
template<int BF16>
__global__ __launch_bounds__(256) void proj_kernel(const void* __restrict__ points)
{
    if (g_isbf16 != BF16) return;
    __shared__ u16 bufP[64 * DIM];               // 32 KB swizzled points tile
    const int rb = blockIdx.x;                   // 0..31
    const int b  = blockIdx.y;                   // 0..3
    const int t  = threadIdx.x;
    const int r0 = rb * 64;
    for (int cc = t; cc < 64 * 32; cc += 256) {
        int r = cc >> 5, kc = cc & 31;
        bf16x8 v = ldfrag<BF16>(points, ((size_t)b * NPT + r0 + r) * DIM + (kc << 3));
        *(bf16x8*)(bufP + r * DIM + ((kc ^ (r & 7)) << 3)) = v;
    }
    __syncthreads();
    const int w = t >> 6, lane = t & 63;
    const int rw = w << 4;
    const int q4 = lane >> 4, l15 = lane & 15;
    const int arow = rw + l15;
    bf16x8 afr[8];
    #pragma unroll
    for (int kt = 0; kt < 8; ++kt)
        afr[kt] = *(const bf16x8*)(bufP + arow * DIM + ((((kt << 2) + q4) ^ (arow & 7)) << 3));
    const u16* WpK = g_wpack + 1 * DIM * DIM;
    const u16* WpV = g_wpack + 2 * DIM * DIM;
    #pragma unroll 1
    for (int ct = 0; ct < 16; ++ct) {
        const int colg = (ct << 4) + l15;
        const int fbase = ((ct << 3) * 64 + lane) << 3;
        f32x4 accK = {0.f,0.f,0.f,0.f}, accV = {0.f,0.f,0.f,0.f};
        #pragma unroll
        for (int kt = 0; kt < 8; ++kt) {
            bf16x8 bfrK = *(const bf16x8*)(WpK + fbase + (kt << 9));
            bf16x8 bfrV = *(const bf16x8*)(WpV + fbase + (kt << 9));
            accK = __builtin_amdgcn_mfma_f32_16x16x32_bf16(afr[kt], bfrK, accK, 0, 0, 0);
            accV = __builtin_amdgcn_mfma_f32_16x16x32_bf16(afr[kt], bfrV, accV, 0, 0, 0);
        }
        #pragma unroll
        for (int reg = 0; reg < 4; ++reg) {
            const int rr = r0 + rw + (q4 << 2) + reg;
            g_kmat[((size_t)b * NPT + rr) * DIM + colg] = f2bf(accK[reg]);
            g_vmat[((size_t)b * NPT + rr) * DIM + colg] = f2bf(accV[reg]);
        }
    }
}

// ---------------------------------------------------------------------------
// Kernel A: exact 16-NN per query. f64 distances, index in low mantissa bits.
// ---------------------------------------------------------------------------
template<int BF16>
__global__ __launch_bounds__(256) void knn_kernel(const void* __restrict__ xyz_q,
                                                  const void* __restrict__ xyz)
{
    if (g_isbf16 != BF16) return;
    __shared__ float4 pts[NPT];                  // 32 KB
    const int b  = blockIdx.x >> 10;
    const int q0 = (blockIdx.x & 1023) << 2;
    const int t  = threadIdx.x;
    for (int i = t; i < NPT; i += 256) {
        const size_t base = ((size_t)b * NPT + i) * 3;
        pts[i] = make_float4(ldf<BF16>(xyz, base + 0),
                             ldf<BF16>(xyz, base + 1),
                             ldf<BF16>(xyz, base + 2), 0.f);
    }
    __syncthreads();

    const int w = t >> 6, lane = t & 63;
    const int q = q0 + w;
    const size_t qb = ((size_t)b * NQ + q) * 3;
    const double qx = (double)ldf<BF16>(xyz_q, qb + 0);
    const double qy = (double)ldf<BF16>(xyz_q, qb + 1);
    const double qz = (double)ldf<BF16>(xyz_q, qb + 2);

    u64 key[32];
    #pragma unroll
    for (int i = 0; i < 32; ++i) {
        const int n = (i << 6) + lane;
        float4 p = pts[n];
        double dx = qx - (double)p.x;
        double dy = qy - (double)p.y;
        double dz = qz - (double)p.z;
        double d2 = fma(dx, dx, fma(dy, dy, dz * dz));   // >= 0
        key[i] = (((u64)__double_as_longlong(d2)) & 0xFFFFFFFFFFFFF800ULL) | (u64)n;
    }
    u64 gmin[4];
    #pragma unroll
    for (int j = 0; j < 4; ++j) {
        u64 mn = key[8 * j];
        #pragma unroll
        for (int i = 1; i < 8; ++i) { u64 k2 = key[8 * j + i]; mn = k2 < mn ? k2 : mn; }
        gmin[j] = mn;
    }
    int* outp = g_knn + ((size_t)b * NQ + q) * KNN_;
    #pragma unroll 1
    for (int r = 0; r < KNN_; ++r) {
        u64 m01 = gmin[0] < gmin[1] ? gmin[0] : gmin[1];
        u64 m23 = gmin[2] < gmin[3] ? gmin[2] : gmin[3];
        u64 m   = m01 < m23 ? m01 : m23;
        #pragma unroll
        for (int off = 32; off >= 1; off >>= 1) {
            u64 o = __shfl_xor(m, off);
            m = o < m ? o : m;
        }
        if (lane == 0) outp[r] = (int)(m & 0x7FF);
        #pragma unroll
        for (int j = 0; j < 4; ++j) {
            if (gmin[j] == m) {
                u64 mn = ~0ULL;
                #pragma unroll
                for (int i = 0; i < 8; ++i) {
                    u64 k2 = key[8 * j + i];
                    k2 = (k2 == m) ? ~0ULL : k2;
                    key[8 * j + i] = k2;
                    mn = k2 < mn ? k2 : mn;
                }
                gmin[j] = mn;
            }
        }
    }
}

// ---------------------------------------------------------------------------
// Kernel B: per-batch q_attn, v_global, attn_g = MLP2(q_attn - k_global).
// ---------------------------------------------------------------------------
template<int BF16>
__global__ __launch_bounds__(256) void gtok_kernel(const void* __restrict__ lat,
    const void* __restrict__ Wq,  const void* __restrict__ Wkg, const void* __restrict__ Wvg,
    const void* __restrict__ Wg1, const void* __restrict__ bg1,
    const void* __restrict__ Wg2, const void* __restrict__ bg2)
{
    if (g_isbf16 != BF16) return;
    const int b = blockIdx.x, t = threadIdx.x;
    __shared__ float latS[DIM], xS[DIM], hS[DIM];
    latS[t] = ldf<BF16>(lat, (size_t)b * DIM + t);
    __syncthreads();
    float sq = 0.f, sk = 0.f, sv = 0.f;
    for (int i = 0; i < DIM; ++i) {
        float x = latS[i];
        sq += x * ldf<BF16>(Wq,  (size_t)t * DIM + i);
        sk += x * ldf<BF16>(Wkg, (size_t)t * DIM + i);
        sv += x * ldf<BF16>(Wvg, (size_t)t * DIM + i);
    }
    g_qattn[b * DIM + t] = sq;
    g_vglob[b * DIM + t] = sv;
    xS[t] = sq - sk;
    __syncthreads();
    float h = 0.f;
    for (int i = 0; i < DIM; ++i) h += xS[i] * ldf<BF16>(Wg1, (size_t)t * DIM + i);
    h += ldf<BF16>(bg1, t);
    hS[t] = fmaxf(h, 0.f);
    __syncthreads();
    float a = 0.f;
    for (int i = 0; i < DIM; ++i) a += hS[i] * ldf<BF16>(Wg2, (size_t)t * DIM + i);
    a += ldf<BF16>(bg2, t);
    g_attng[b * DIM + t] = a;
}

// ---------------------------------------------------------------------------
// Kernel C: fused attention. Block = 256 thr = 4 waves = 4 queries = 64 rows.
// SINGLE 32 KB LDS buffer (42 KB total -> 3 blocks/CU = 12 waves/CU):
//   bufA timeline: V-gather -> (V lifted to 32 packed VGPRs) -> h1 ->
//                  K-gather -> attn_in -> g1.
// vp = bf16(V+pos) lives in 32 packed u32 VGPRs from stage 2 to stage 4.
// ---------------------------------------------------------------------------
template<int BF16>
__global__ __launch_bounds__(256) void attn_kernel(
    const void* __restrict__ xyz_q, const void* __restrict__ xyz,
    const void* __restrict__ Wd1, const void* __restrict__ bd1,
    const void* __restrict__ bd2, const void* __restrict__ bg1,
    const void* __restrict__ bg2,
    void* __restrict__ out)
{
    if (g_isbf16 != BF16) return;
    __shared__ u16 bufA[64 * DIM];               // 32 KB, time-shared
    __shared__ int nbrS[64];
    __shared__ float wd1S[DIM * 4];              // (w0,w1,w2,bd1) per output col
    __shared__ float qaS[DIM], agS[DIM], vgS[DIM];
    __shared__ float bd2S[DIM], bg1S[DIM], bg2S[DIM];

    const int b  = blockIdx.x >> 10;
    const int q0 = (blockIdx.x & 1023) << 2;
    const int t  = threadIdx.x;

    // ---- stage 0: small shared data (the ONLY barrier-protected stage)
    wd1S[t * 4 + 0] = ldf<BF16>(Wd1, (size_t)t * 3 + 0);
    wd1S[t * 4 + 1] = ldf<BF16>(Wd1, (size_t)t * 3 + 1);
    wd1S[t * 4 + 2] = ldf<BF16>(Wd1, (size_t)t * 3 + 2);
    wd1S[t * 4 + 3] = ldf<BF16>(bd1, t);
    bd2S[t] = ldf<BF16>(bd2, t);
    bg1S[t] = ldf<BF16>(bg1, t);
    bg2S[t] = ldf<BF16>(bg2, t);
    qaS[t] = g_qattn[b * DIM + t];
    agS[t] = g_attng[b * DIM + t];
    vgS[t] = g_vglob[b * DIM + t];
    if (t < 64) {
        int qq = q0 + (t >> 4);
        nbrS[t] = g_knn[((size_t)b * NQ + qq) * KNN_ + (t & 15)];
    }
    __syncthreads();

    const int w = t >> 6, lane = t & 63;
    const int q  = q0 + w;                       // one query per wave
    const int rw = w << 4;                       // this wave's 16 rows
    const int q4 = lane >> 4, l15 = lane & 15;
    const int arow = rw + l15;
    const int rgath = rw + (lane >> 2);          // gather row for this lane
    const int kcb   = lane & 3;                  // gather chunk base

    // packed-weight bases (fragment order): frag index = (ct*8+kt)*64 + lane
    const u16* WpD2 = g_wpack + 0 * DIM * DIM;
    const u16* WpG1 = g_wpack + 3 * DIM * DIM;
    const u16* WpG2 = g_wpack + 4 * DIM * DIM;

    // ---- stage V: gather this wave's 16 neighbor V rows into bufA, then
    //      lift to C-layout packed registers (raw bf16 bits, no conversion).
    {
        const size_t vb = ((size_t)b * NPT + nbrS[rgath]) * DIM;
        #pragma unroll
        for (int ci = 0; ci < 8; ++ci) {
            const int kc = kcb + (ci << 2);
            *(bf16x8*)(bufA + rgath * DIM + ((kc ^ (rgath & 7)) << 3)) =
                *(const bf16x8*)(g_vmat + vb + (kc << 3));
        }
    }
    u32 vp[32];                                   // V (later V+pos), C-layout
    {
        const int r0v = rw + (q4 << 2);
        #pragma unroll
        for (int ct = 0; ct < 16; ++ct) {
            const int colg = (ct << 4) + l15;
            vp[(ct << 1) + 0] = (u32)bufA[swz(r0v + 0, colg)]
                              | ((u32)bufA[swz(r0v + 1, colg)] << 16);
            vp[(ct << 1) + 1] = (u32)bufA[swz(r0v + 2, colg)]
                              | ((u32)bufA[swz(r0v + 3, colg)] << 16);
        }
    }

    // ---- stage 1: h1 = relu(d @ Wd1^T + bd1) -> bufA (over consumed V;
    //      in-order DS pipe: all lanes' V reads precede these writes)
    {
        const int n = nbrS[rgath];
        const size_t nb3 = ((size_t)b * NPT + n) * 3;
        const size_t qb3 = ((size_t)b * NQ  + q) * 3;
        const float dx = ldf<BF16>(xyz_q, qb3 + 0) - ldf<BF16>(xyz, nb3 + 0);
        const float dy = ldf<BF16>(xyz_q, qb3 + 1) - ldf<BF16>(xyz, nb3 + 1);
        const float dz = ldf<BF16>(xyz_q, qb3 + 2) - ldf<BF16>(xyz, nb3 + 2);
        #pragma unroll
        for (int ci = 0; ci < 8; ++ci) {
            const int kc = kcb + (ci << 2);
            u32 hw[4];
            #pragma unroll
            for (int pp = 0; pp < 4; ++pp) {
                const int c = (kc << 3) + pp * 2;
                const float* wv0 = wd1S + (size_t)c * 4;
                const float* wv1 = wd1S + (size_t)(c + 1) * 4;
                float h0 = wv0[0] * dx + wv0[1] * dy + wv0[2] * dz + wv0[3];
                float h1 = wv1[0] * dx + wv1[1] * dy + wv1[2] * dz + wv1[3];
                hw[pp] = (u32)f2bf(fmaxf(h0, 0.f)) | ((u32)f2bf(fmaxf(h1, 0.f)) << 16);
            }
            *(uint4*)(bufA + rgath * DIM + ((kc ^ (rgath & 7)) << 3)) = make_uint4(hw[0], hw[1], hw[2], hw[3]);
        }
    }

    // h1 fragments from LDS (consumes bufA h1)
    bf16x8 afrA[8];
    #pragma unroll
    for (int kt = 0; kt < 8; ++kt)
        afrA[kt] = *(const bf16x8*)(bufA + arow * DIM + ((((kt << 2) + q4) ^ (arow & 7)) << 3));

    // ---- stage K: gather precomputed K rows into bufA (over consumed h1)
    {
        const size_t kb = ((size_t)b * NPT + nbrS[rgath]) * DIM;
        #pragma unroll
        for (int ci = 0; ci < 8; ++ci) {
            const int kc = kcb + (ci << 2);
            *(bf16x8*)(bufA + rgath * DIM + ((kc ^ (rgath & 7)) << 3)) =
                *(const bf16x8*)(g_kmat + kb + (kc << 3));
        }
    }

    // ---- stage 2: pos = h1@Wd2^T + bd2; attn_in = (qa-K)+pos -> bufA;
    //      vp := bf16(V + pos) in-register.
    #pragma unroll 1
    for (int ct = 0; ct < 16; ++ct) {
        const int colg = (ct << 4) + l15;
        const int fbase = ((ct << 3) * 64 + lane) << 3;   // + kt*512 per kt
        f32x4 aP = {0.f,0.f,0.f,0.f};
        #pragma unroll
        for (int kt = 0; kt < 8; ++kt) {
            bf16x8 bfrD = *(const bf16x8*)(WpD2 + fbase + (kt << 9));
            aP = __builtin_amdgcn_mfma_f32_16x16x32_bf16(afrA[kt], bfrD, aP, 0, 0, 0);
        }
        const float bb = bd2S[colg];
        const float qa = qaS[colg];
        const u32 p01 = vp[(ct << 1) + 0];
        const u32 p23 = vp[(ct << 1) + 1];
        u16 nb[4];
        #pragma unroll
        for (int reg = 0; reg < 4; ++reg) {
            const int ad = swz(rw + (q4 << 2) + reg, colg);
            const float pv = aP[reg] + bb;
            const float kv = bf2f(bufA[ad]);
            bufA[ad] = f2bf((qa - kv) + pv);
            const u32 praw = (reg < 2) ? p01 : p23;
            const float vv = bf2f((u16)((reg & 1) ? (praw >> 16) : (praw & 0xFFFF)));
            nb[reg] = f2bf(vv + pv);
        }
        vp[(ct << 1) + 0] = (u32)nb[0] | ((u32)nb[1] << 16);
        vp[(ct << 1) + 1] = (u32)nb[2] | ((u32)nb[3] << 16);
    }

    // ---- stage 3: g1 = relu(attn_in@Wg1^T + bg1) -> bufA
    #pragma unroll
    for (int kt = 0; kt < 8; ++kt)
        afrA[kt] = *(const bf16x8*)(bufA + arow * DIM + ((((kt << 2) + q4) ^ (arow & 7)) << 3));
    #pragma unroll 1
    for (int ct = 0; ct < 16; ++ct) {
        const int colg = (ct << 4) + l15;
        const int fbase = ((ct << 3) * 64 + lane) << 3;
        f32x4 acc = {0.f,0.f,0.f,0.f};
        #pragma unroll
        for (int kt = 0; kt < 8; ++kt) {
            bf16x8 bfr = *(const bf16x8*)(WpG1 + fbase + (kt << 9));
            acc = __builtin_amdgcn_mfma_f32_16x16x32_bf16(afrA[kt], bfr, acc, 0, 0, 0);
        }
        const float bb = bg1S[colg];
        #pragma unroll
        for (int reg = 0; reg < 4; ++reg) {
            const int rr = rw + (q4 << 2) + reg;
            bufA[swz(rr, colg)] = f2bf(fmaxf(acc[reg] + bb, 0.f));
        }
    }

    // ---- stage 4: logits = g1@Wg2^T + bg2; softmax over 16 nbrs + global;
    //               out = (sum_j w_j * vp_j + w_g * v_global) / Z
    #pragma unroll
    for (int kt = 0; kt < 8; ++kt)
        afrA[kt] = *(const bf16x8*)(bufA + arow * DIM + ((((kt << 2) + q4) ^ (arow & 7)) << 3));
    const size_t outq = ((size_t)b * NQ + q) * DIM;
    #pragma unroll 1
    for (int ct = 0; ct < 16; ++ct) {
        const int colg = (ct << 4) + l15;
        const int fbase = ((ct << 3) * 64 + lane) << 3;
        f32x4 accL = {0.f,0.f,0.f,0.f};
        #pragma unroll
        for (int kt = 0; kt < 8; ++kt) {
            bf16x8 bfrG = *(const bf16x8*)(WpG2 + fbase + (kt << 9));
            accL = __builtin_amdgcn_mfma_f32_16x16x32_bf16(afrA[kt], bfrG, accL, 0, 0, 0);
        }
        const float bb = bg2S[colg];
        const float l0 = accL[0] + bb;
        const float l1 = accL[1] + bb;
        const float l2 = accL[2] + bb;
        const float l3 = accL[3] + bb;
        const float gl = agS[colg];
        float mx = fmaxf(fmaxf(l0, l1), fmaxf(l2, l3));
        mx = fmaxf(mx, __shfl_xor(mx, 16));
        mx = fmaxf(mx, __shfl_xor(mx, 32));
        mx = fmaxf(mx, gl);
        const float e0 = expf(l0 - mx), e1 = expf(l1 - mx);
        const float e2 = expf(l2 - mx), e3 = expf(l3 - mx);
        float s = (e0 + e1) + (e2 + e3);
        s += __shfl_xor(s, 16);
        s += __shfl_xor(s, 32);
        const float eg  = expf(gl - mx);
        const float inv = 1.0f / (s + eg);
        const u32 p01 = vp[(ct << 1) + 0];
        const u32 p23 = vp[(ct << 1) + 1];
        float o = e0 * bf2f((u16)(p01 & 0xFFFF))
                + e1 * bf2f((u16)(p01 >> 16))
                + e2 * bf2f((u16)(p23 & 0xFFFF))
                + e3 * bf2f((u16)(p23 >> 16));
        o += __shfl_xor(o, 16);
        o += __shfl_xor(o, 32);
        o = (o + eg * vgS[colg]) * inv;
        if (lane < 16) {
            if (BF16) ((u16*)out)[outq + colg] = f2bf(o);
            else      ((float*)out)[outq + colg] = o;
        }
    }
}

// ---------------------------------------------------------------------------
extern "C" void kernel_launch(void* const* d_in, const int* in_sizes, int n_in,
                              void* d_out, int out_size, void* d_ws, size_t ws_size,
                              hipStream_t stream)
{
    const void* xyz_q  = d_in[0];
    const void* lat    = d_in[1];
    const void* xyz    = d_in[2];
    const void* points = d_in[3];
    const void* Wd1 = d_in[4];
    const void* bd1 = d_in[5];
    const void* Wd2 = d_in[6];
    const void* bd2 = d_in[7];
    const void* Wg1 = d_in[8];
    const void* bg1 = d_in[9];
    const void* Wg2 = d_in[10];
    const void* bg2 = d_in[11];
    const void* Wkg = d_in[12];
    const void* Wvg = d_in[13];
    const void* Wq  = d_in[14];
    const void* Wk  = d_in[15];
    const void* Wv  = d_in[16];

    probe_kernel<<<1, 64, 0, stream>>>((const u32*)lat);

    repack_kernel<1><<<dim3(32, 5), 256, 0, stream>>>(Wd2, Wk, Wv, Wg1, Wg2);
    repack_kernel<0><<<dim3(32, 5), 256, 0, stream>>>(Wd2, Wk, Wv, Wg1, Wg2);
    proj_kernel<1><<<dim3(32, 4), 256, 0, stream>>>(points);
    proj_kernel<0><<<dim3(32, 4), 256, 0, stream>>>(points);
    knn_kernel<1><<<4096, 256, 0, stream>>>(xyz_q, xyz);
    knn_kernel<0><<<4096, 256, 0, stream>>>(xyz_q, xyz);
    gtok_kernel<1><<<4, 256, 0, stream>>>(lat, Wq, Wkg, Wvg, Wg1, bg1, Wg2, bg2);
    gtok_kernel<0><<<4, 256, 0, stream>>>(lat, Wq, Wkg, Wvg, Wg1, bg1, Wg2, bg2);
    attn_kernel<1><<<4096, 256, 0, stream>>>(xyz_q, xyz,
                                             Wd1, bd1, bd2, bg1, bg2, d_out);
    attn_kernel<0><<<4096, 256, 0, stream>>>(xyz_q, xyz,
                                             Wd1, bd1, bd2, bg1, bg2, d_out);
}